// Round 4
// baseline (8535.187 us; speedup 1.0000x reference)
//
#include <hip/hip_runtime.h>
#include <hip/hip_bf16.h>

#define NFEAT   128
#define NATTRI  500
#define NNODES  100000
#define NEDGES  3200000

typedef __hip_bfloat16 bf16;

__device__ __forceinline__ float sigmoidf_(float x) { return 1.0f / (1.0f + __expf(-x)); }

__device__ __forceinline__ float ldf(const float* p) { return *p; }
__device__ __forceinline__ float ldf(const bf16* p)  { return __bfloat162float(*p); }

// ---------------------------------------------------------------------------
// Hacc = H^T @ emb_attr, naive: one block per node, block-uniform H reads.
// ---------------------------------------------------------------------------
__global__ __launch_bounds__(128) void k_hacc(
    const float* __restrict__ emb_attr,   // [500][128]
    const float* __restrict__ H,          // [500][100000]
    float* __restrict__ Hacc)             // [100000][128]
{
  const int n = blockIdx.x;
  const int t = threadIdx.x;
  float acc = 0.f;
  for (int a = 0; a < NATTRI; ++a) {
    float h = H[(size_t)a * NNODES + n];
    if (h > 0.5f) acc += emb_attr[a * 128 + t];
  }
  Hacc[(size_t)n * 128 + t] = acc;
}

// ---------------------------------------------------------------------------
// loss_recon partial sums. 64-node tile per block, 32-attr chunks in LDS.
// ---------------------------------------------------------------------------
__global__ __launch_bounds__(256) void k_loss(
    const float* __restrict__ emb_attr,
    const float* __restrict__ emb_node,
    const float* __restrict__ H,
    float* __restrict__ loss_acc)
{
  __shared__ __align__(16) float sA[32 * 132];
  __shared__ float red[4];

  const int t  = threadIdx.x;
  const int n0 = blockIdx.x * 64;
  const int a2 = (t >> 4) * 2;
  const int n4 = (t & 15) * 4;
  const bool nvalid = (n0 + n4) < NNODES;

  const float* nr[4];
  #pragma unroll
  for (int j = 0; j < 4; ++j) {
    int n = n0 + n4 + j;
    nr[j] = emb_node + (size_t)(n < NNODES ? n : 0) * 128;
  }

  float lacc = 0.f;

  for (int c = 0; c < NATTRI; c += 32) {
    const int cnt = min(32, NATTRI - c);
    __syncthreads();
    for (int f = t; f < cnt * 32; f += 256) {
      int row = f >> 5, col = (f & 31) << 2;
      *(float4*)&sA[row * 132 + col] = *(const float4*)&emb_attr[(c + row) * 128 + col];
    }
    __syncthreads();

    if (a2 < cnt && nvalid) {
      float acc[2][4] = {{0.f,0.f,0.f,0.f},{0.f,0.f,0.f,0.f}};
      for (int k = 0; k < 128; k += 4) {
        float4 a0 = *(const float4*)&sA[a2 * 132 + k];
        float4 a1 = *(const float4*)&sA[(a2 + 1) * 132 + k];
        #pragma unroll
        for (int j = 0; j < 4; ++j) {
          float4 nv = *(const float4*)&nr[j][k];
          acc[0][j] += a0.x*nv.x + a0.y*nv.y + a0.z*nv.z + a0.w*nv.w;
          acc[1][j] += a1.x*nv.x + a1.y*nv.y + a1.z*nv.z + a1.w*nv.w;
        }
      }
      #pragma unroll
      for (int i = 0; i < 2; ++i) {
        int a = c + a2 + i;
        float4 h4 = *(const float4*)&H[(size_t)a * NNODES + n0 + n4];
        float hv[4] = {h4.x, h4.y, h4.z, h4.w};
        #pragma unroll
        for (int j = 0; j < 4; ++j) {
          float s = sigmoidf_(acc[i][j]);
          if (hv[j] > 0.5f) { float d = 1.f - s; lacc += 2.0f * d * d; }
          else              { lacc += 0.1f * s * s; }
        }
      }
    }
  }
  float tot = lacc;
  for (int off = 32; off; off >>= 1) tot += __shfl_down(tot, off, 64);
  if ((t & 63) == 0) red[t >> 6] = tot;
  __syncthreads();
  if (t == 0) atomicAdd(loss_acc, red[0] + red[1] + red[2] + red[3]);
}

// ---------------------------------------------------------------------------
// CSR build
// ---------------------------------------------------------------------------
__global__ __launch_bounds__(256) void k_hist(const int* __restrict__ g_row,
                                              int* __restrict__ deg) {
  int e = blockIdx.x * 256 + threadIdx.x;
  if (e < NEDGES) atomicAdd(&deg[g_row[e]], 1);
}

__global__ __launch_bounds__(256) void k_scan(const int* __restrict__ deg,
                                              int* __restrict__ row_ptr,
                                              int* __restrict__ cursor) {
  __shared__ int part[256];
  __shared__ int excl[257];
  const int t = threadIdx.x;
  const int CH = (NNODES + 255) / 256;
  int base = t * CH;
  int s = 0;
  for (int i = 0; i < CH; ++i) { int idx = base + i; if (idx < NNODES) s += deg[idx]; }
  part[t] = s;
  __syncthreads();
  if (t == 0) {
    int r = 0;
    for (int i = 0; i < 256; ++i) { excl[i] = r; r += part[i]; }
    excl[256] = r;
    row_ptr[NNODES] = r;
  }
  __syncthreads();
  int run = excl[t];
  for (int i = 0; i < CH; ++i) {
    int idx = base + i;
    if (idx < NNODES) { int d = deg[idx]; row_ptr[idx] = run; cursor[idx] = run; run += d; }
  }
}

__global__ __launch_bounds__(256) void k_scatter(
    const int* __restrict__ g_row, const int* __restrict__ g_col,
    const float* __restrict__ g_val, int* __restrict__ cursor,
    int* __restrict__ col_s, float* __restrict__ val_s) {
  int e = blockIdx.x * 256 + threadIdx.x;
  if (e < NEDGES) {
    int r = g_row[e];
    int p = atomicAdd(&cursor[r], 1);
    col_s[p] = g_col[e];
    val_s[p] = g_val[e];
  }
}

// ---------------------------------------------------------------------------
// Naive GEMM: one thread per output element. Y[n][c] = X@W + b.
// ---------------------------------------------------------------------------
template<int TWO, typename ST>
__global__ __launch_bounds__(256) void k_gemm_naive(
    const ST* __restrict__ X0, const float* __restrict__ X1,
    const float* __restrict__ W, const float* __restrict__ bias,
    float* __restrict__ Y)
{
  int gid = blockIdx.x * 256 + threadIdx.x;   // grid covers exactly NNODES*128
  int n = gid >> 7;
  int c = gid & 127;
  float acc = bias[c];
  const ST* x0 = X0 + (size_t)n * 128;
  #pragma unroll 8
  for (int k = 0; k < 128; ++k)
    acc = fmaf(ldf(&x0[k]), W[k * 128 + c], acc);
  if (TWO) {
    const float* x1 = X1 + (size_t)n * 128;
    #pragma unroll 8
    for (int k = 0; k < 128; ++k)
      acc = fmaf(x1[k], W[(128 + k) * 128 + c], acc);
  }
  Y[(size_t)n * 128 + c] = acc;
}

// ---------------------------------------------------------------------------
// SpMM via CSR: wave per row, 2 feats/lane, no atomics.
// ---------------------------------------------------------------------------
__global__ __launch_bounds__(256) void k_spmm(
    const int* __restrict__ row_ptr, const int* __restrict__ col_s,
    const float* __restrict__ val_s, const float* __restrict__ X,
    float* __restrict__ Y)
{
  int w = (int)((blockIdx.x * 256u + threadIdx.x) >> 6);
  int lane = threadIdx.x & 63;
  if (w >= NNODES) return;
  int s = row_ptr[w], e = row_ptr[w + 1];
  int f = lane * 2;
  float ax = 0.f, ay = 0.f;
  for (int i = s; i < e; ++i) {
    int c = col_s[i];
    float v = val_s[i];
    float2 xv = *(const float2*)&X[(size_t)c * 128 + f];
    ax += v * xv.x; ay += v * xv.y;
  }
  float2 o; o.x = ax; o.y = ay;
  *(float2*)&Y[(size_t)w * 128 + f] = o;
}

// ---------------------------------------------------------------------------
// f32 -> bf16 conversion (fallback path only).
// ---------------------------------------------------------------------------
__global__ __launch_bounds__(256) void k_cvt(const float* __restrict__ src,
                                             bf16* __restrict__ dst)
{
  size_t i = (size_t)blockIdx.x * 256 + threadIdx.x;
  dst[i] = __float2bfloat16(src[i]);
}

// ---------------------------------------------------------------------------
// Gather with fused l2norm; f32 output. Wave per output row.
// ---------------------------------------------------------------------------
template<typename ST>
__global__ __launch_bounds__(256) void k_gather(
    const ST* __restrict__ s1, const ST* __restrict__ s2,
    const int* __restrict__ i0, const int* __restrict__ i1,
    const int* __restrict__ i2, const int* __restrict__ i3,
    float* __restrict__ out)
{
  long gw = ((long)blockIdx.x * 256 + threadIdx.x) >> 6;   // 0..799999
  int lane = threadIdx.x & 63;
  int o   = (int)(gw / 200000);
  int rem = (int)(gw % 200000);
  int l = rem / 100000;
  int i = rem % 100000;
  const int* idx = (o == 0) ? i0 : (o == 1) ? i1 : (o == 2) ? i2 : i3;
  int node = idx[i];
  const ST* src = (l == 0) ? s1 : s2;
  float vx = ldf(&src[(size_t)node * 128 + lane * 2 + 0]);
  float vy = ldf(&src[(size_t)node * 128 + lane * 2 + 1]);
  float ss = vx * vx + vy * vy;
  for (int off = 32; off; off >>= 1) ss += __shfl_xor(ss, off, 64);
  float inv = 1.0f / fmaxf(sqrtf(ss), 1e-12f);
  float2 ov; ov.x = vx * inv; ov.y = vy * inv;
  *(float2*)&out[gw * 128 + lane * 2] = ov;
}

__global__ void k_loss_final(const float* __restrict__ loss_acc, float* __restrict__ out) {
  if (threadIdx.x == 0)
    out[102400000] = loss_acc[0] * (1.0f / 50000000.0f);
}

// ---------------------------------------------------------------------------
extern "C" void kernel_launch(void* const* d_in, const int* in_sizes, int n_in,
                              void* d_out, int out_size, void* d_ws, size_t ws_size,
                              hipStream_t stream)
{
  const float* emb_attr = (const float*)d_in[0];
  const float* emb_node = (const float*)d_in[1];
  const float* W0 = (const float*)d_in[2];
  const float* b0 = (const float*)d_in[3];
  const float* W1 = (const float*)d_in[4];
  const float* b1 = (const float*)d_in[5];
  const float* H  = (const float*)d_in[6];
  const float* g_val = (const float*)d_in[7];
  const int* g_row = (const int*)d_in[8];
  const int* g_col = (const int*)d_in[9];
  const int* pos_src = (const int*)d_in[10];
  const int* pos_dst = (const int*)d_in[11];
  const int* neg_src = (const int*)d_in[12];
  const int* neg_dst = (const int*)d_in[13];
  float* out = (float*)d_out;     // REFERENCE OUTPUT DTYPE IS FLOAT32

  const size_t NF = 12800000;     // elements per node-feature buffer

  // d_out (409.6 MB) doubles as scratch for everything dead before the final
  // gather (k_gather + k_loss_final overwrite every output element).
  float* F = (float*)d_out;
  float* Hacc    = F;                         // 12.8M f32
  float* y       = F + NF;                    // 12.8M f32
  int*   row_ptr = (int*)(F + 2 * NF);        // 100001 (padded 100004)
  int*   deg     = row_ptr + 100004;          // 100000
  int*   cursor  = deg + 100000;              // 100000
  int*   col_s   = cursor + 100000;           // 3.2M
  float* val_s   = (float*)(col_s + 3200000); // 3.2M
  float* T       = val_s + 3200000;           // 12.8M (fallback only)
                                              // ends at ~45.1M < 102.4M f32

  const int gemm_grid = (NNODES * 128) / 256;   // 50000
  const int spmm_grid = (NNODES * 64) / 256;    // 25000
  const int cvt_grid  = (int)(NF / 256);        // 50000

  if (ws_size >= NF * 8 + 16) {
    // -------- main path: f32 s1/s2 in d_ws --------
    float* s1 = (float*)d_ws;
    float* s2 = s1 + NF;
    float* loss_acc = s2 + NF;

    hipMemsetAsync(loss_acc, 0, 16, stream);
    hipMemsetAsync(deg, 0, NNODES * sizeof(int), stream);

    k_hacc<<<NNODES, 128, 0, stream>>>(emb_attr, H, Hacc);
    k_loss<<<(NNODES + 63) / 64, 256, 0, stream>>>(emb_attr, emb_node, H, loss_acc);

    k_hist<<<(NEDGES + 255) / 256, 256, 0, stream>>>(g_row, deg);
    k_scan<<<1, 256, 0, stream>>>(deg, row_ptr, cursor);
    k_scatter<<<(NEDGES + 255) / 256, 256, 0, stream>>>(g_row, g_col, g_val, cursor, col_s, val_s);

    k_gemm_naive<1, float><<<gemm_grid, 256, 0, stream>>>(emb_node, Hacc, W0, b0, y);
    k_spmm<<<spmm_grid, 256, 0, stream>>>(row_ptr, col_s, val_s, y, s1);
    k_gemm_naive<0, float><<<gemm_grid, 256, 0, stream>>>(s1, s1, W1, b1, y);
    k_spmm<<<spmm_grid, 256, 0, stream>>>(row_ptr, col_s, val_s, y, s2);

    k_gather<float><<<200000, 256, 0, stream>>>(s1, s2, pos_src, pos_dst, neg_src, neg_dst, out);
    k_loss_final<<<1, 64, 0, stream>>>(loss_acc, out);
  } else {
    // -------- fallback: bf16 s1/s2 in d_ws (51.2MB + 16B) --------
    bf16* s1 = (bf16*)d_ws;
    bf16* s2 = s1 + NF;
    float* loss_acc = (float*)(s2 + NF);

    hipMemsetAsync(loss_acc, 0, 16, stream);
    hipMemsetAsync(deg, 0, NNODES * sizeof(int), stream);

    k_hacc<<<NNODES, 128, 0, stream>>>(emb_attr, H, Hacc);
    k_loss<<<(NNODES + 63) / 64, 256, 0, stream>>>(emb_attr, emb_node, H, loss_acc);

    k_hist<<<(NEDGES + 255) / 256, 256, 0, stream>>>(g_row, deg);
    k_scan<<<1, 256, 0, stream>>>(deg, row_ptr, cursor);
    k_scatter<<<(NEDGES + 255) / 256, 256, 0, stream>>>(g_row, g_col, g_val, cursor, col_s, val_s);

    k_gemm_naive<1, float><<<gemm_grid, 256, 0, stream>>>(emb_node, Hacc, W0, b0, y);
    k_spmm<<<spmm_grid, 256, 0, stream>>>(row_ptr, col_s, val_s, y, T);
    k_cvt<<<cvt_grid, 256, 0, stream>>>(T, s1);

    k_gemm_naive<0, bf16><<<gemm_grid, 256, 0, stream>>>(s1, (const float*)nullptr, W1, b1, y);
    k_spmm<<<spmm_grid, 256, 0, stream>>>(row_ptr, col_s, val_s, y, T);
    k_cvt<<<cvt_grid, 256, 0, stream>>>(T, s2);

    k_gather<bf16><<<200000, 256, 0, stream>>>(s1, s2, pos_src, pos_dst, neg_src, neg_dst, out);
    k_loss_final<<<1, 64, 0, stream>>>(loss_acc, out);
  }
}

// Round 7
// 3631.136 us; speedup vs baseline: 2.3506x; 2.3506x over previous
//
#include <hip/hip_runtime.h>
#include <hip/hip_bf16.h>

#define NFEAT   128
#define NATTRI  500
#define NNODES  100000
#define NEDGES  3200000
#define HCAP    8000000   // capacity of hattr list (expected ~500K nz)

typedef __hip_bfloat16 bf16;

__device__ __forceinline__ float sigmoidf_(float x) { return 1.0f / (1.0f + __expf(-x)); }

// ---------------------------------------------------------------------------
// H nonzero extraction, pass 1: per-node counts. Coalesced row-major H read.
// grid: (98, NATTRI), block 256, float4 per thread -> 1024 elems per block.
// ---------------------------------------------------------------------------
__global__ __launch_bounds__(256) void k_hnz_count(
    const float* __restrict__ H, int* __restrict__ hcnt)
{
  const int a   = blockIdx.y;
  const int off = blockIdx.x * 1024 + threadIdx.x * 4;
  if (off + 3 < NNODES) {
    float4 h4 = *(const float4*)&H[(size_t)a * NNODES + off];
    if (h4.x > 0.5f) atomicAdd(&hcnt[off + 0], 1);
    if (h4.y > 0.5f) atomicAdd(&hcnt[off + 1], 1);
    if (h4.z > 0.5f) atomicAdd(&hcnt[off + 2], 1);
    if (h4.w > 0.5f) atomicAdd(&hcnt[off + 3], 1);
  } else {
    for (int j = 0; j < 4; ++j) {
      int n = off + j;
      if (n < NNODES && H[(size_t)a * NNODES + n] > 0.5f) atomicAdd(&hcnt[n], 1);
    }
  }
}

// ---------------------------------------------------------------------------
// H nonzero extraction, pass 2: place attr indices at cursor positions.
// ---------------------------------------------------------------------------
__global__ __launch_bounds__(256) void k_hnz_place(
    const float* __restrict__ H, int* __restrict__ hcursor,
    int* __restrict__ hattr)
{
  const int a   = blockIdx.y;
  const int off = blockIdx.x * 1024 + threadIdx.x * 4;
  if (off + 3 < NNODES) {
    float4 h4 = *(const float4*)&H[(size_t)a * NNODES + off];
    float hv[4] = {h4.x, h4.y, h4.z, h4.w};
    #pragma unroll
    for (int j = 0; j < 4; ++j) {
      if (hv[j] > 0.5f) {
        int pos = atomicAdd(&hcursor[off + j], 1);
        if (pos < HCAP) hattr[pos] = a;
      }
    }
  } else {
    for (int j = 0; j < 4; ++j) {
      int n = off + j;
      if (n < NNODES && H[(size_t)a * NNODES + n] > 0.5f) {
        int pos = atomicAdd(&hcursor[n], 1);
        if (pos < HCAP) hattr[pos] = a;
      }
    }
  }
}

// ---------------------------------------------------------------------------
// Hacc[n] = sum over nz attrs a of emb_attr[a]. Wave per node, 2 f/lane.
// ---------------------------------------------------------------------------
__global__ __launch_bounds__(256) void k_hacc_sparse(
    const int* __restrict__ hrow_ptr, const int* __restrict__ hattr,
    const float* __restrict__ emb_attr, float* __restrict__ Hacc)
{
  int n = blockIdx.x * 4 + (threadIdx.x >> 6);
  if (n >= NNODES) return;
  int lane = threadIdx.x & 63;
  int s = hrow_ptr[n], e = min(hrow_ptr[n + 1], HCAP);
  int f = lane * 2;
  float ax = 0.f, ay = 0.f;
  for (int i = s; i < e; ++i) {
    int a = hattr[i];                          // wave-uniform broadcast
    float2 v = *(const float2*)&emb_attr[a * 128 + f];
    ax += v.x; ay += v.y;
  }
  float2 o; o.x = ax; o.y = ay;
  *(float2*)&Hacc[(size_t)n * 128 + f] = o;
}

// ---------------------------------------------------------------------------
// loss_recon partial sums. 64-node tile per block, 32-attr chunks in LDS.
// ---------------------------------------------------------------------------
__global__ __launch_bounds__(256) void k_loss(
    const float* __restrict__ emb_attr,
    const float* __restrict__ emb_node,
    const float* __restrict__ H,
    float* __restrict__ loss_acc)
{
  __shared__ __align__(16) float sA[32 * 132];
  __shared__ float red[4];

  const int t  = threadIdx.x;
  const int n0 = blockIdx.x * 64;
  const int a2 = (t >> 4) * 2;
  const int n4 = (t & 15) * 4;
  const bool nvalid = (n0 + n4) < NNODES;

  const float* nr[4];
  #pragma unroll
  for (int j = 0; j < 4; ++j) {
    int n = n0 + n4 + j;
    nr[j] = emb_node + (size_t)(n < NNODES ? n : 0) * 128;
  }

  float lacc = 0.f;

  for (int c = 0; c < NATTRI; c += 32) {
    const int cnt = min(32, NATTRI - c);
    __syncthreads();
    for (int f = t; f < cnt * 32; f += 256) {
      int row = f >> 5, col = (f & 31) << 2;
      *(float4*)&sA[row * 132 + col] = *(const float4*)&emb_attr[(c + row) * 128 + col];
    }
    __syncthreads();

    if (a2 < cnt && nvalid) {
      float acc[2][4] = {{0.f,0.f,0.f,0.f},{0.f,0.f,0.f,0.f}};
      for (int k = 0; k < 128; k += 4) {
        float4 a0 = *(const float4*)&sA[a2 * 132 + k];
        float4 a1 = *(const float4*)&sA[(a2 + 1) * 132 + k];
        #pragma unroll
        for (int j = 0; j < 4; ++j) {
          float4 nv = *(const float4*)&nr[j][k];
          acc[0][j] += a0.x*nv.x + a0.y*nv.y + a0.z*nv.z + a0.w*nv.w;
          acc[1][j] += a1.x*nv.x + a1.y*nv.y + a1.z*nv.z + a1.w*nv.w;
        }
      }
      #pragma unroll
      for (int i = 0; i < 2; ++i) {
        int a = c + a2 + i;
        float4 h4 = *(const float4*)&H[(size_t)a * NNODES + n0 + n4];
        float hv[4] = {h4.x, h4.y, h4.z, h4.w};
        #pragma unroll
        for (int j = 0; j < 4; ++j) {
          float s = sigmoidf_(acc[i][j]);
          if (hv[j] > 0.5f) { float d = 1.f - s; lacc += 2.0f * d * d; }
          else              { lacc += 0.1f * s * s; }
        }
      }
    }
  }
  float tot = lacc;
  for (int off = 32; off; off >>= 1) tot += __shfl_down(tot, off, 64);
  if ((t & 63) == 0) red[t >> 6] = tot;
  __syncthreads();
  if (t == 0) atomicAdd(loss_acc, red[0] + red[1] + red[2] + red[3]);
}

// ---------------------------------------------------------------------------
// CSR build for the edge graph
// ---------------------------------------------------------------------------
__global__ __launch_bounds__(256) void k_hist(const int* __restrict__ g_row,
                                              int* __restrict__ deg) {
  int e = blockIdx.x * 256 + threadIdx.x;
  if (e < NEDGES) atomicAdd(&deg[g_row[e]], 1);
}

__global__ __launch_bounds__(256) void k_scan(const int* __restrict__ deg,
                                              int* __restrict__ row_ptr,
                                              int* __restrict__ cursor) {
  __shared__ int part[256];
  __shared__ int excl[257];
  const int t = threadIdx.x;
  const int CH = (NNODES + 255) / 256;
  int base = t * CH;
  int s = 0;
  for (int i = 0; i < CH; ++i) { int idx = base + i; if (idx < NNODES) s += deg[idx]; }
  part[t] = s;
  __syncthreads();
  if (t == 0) {
    int r = 0;
    for (int i = 0; i < 256; ++i) { excl[i] = r; r += part[i]; }
    excl[256] = r;
    row_ptr[NNODES] = r;
  }
  __syncthreads();
  int run = excl[t];
  for (int i = 0; i < CH; ++i) {
    int idx = base + i;
    if (idx < NNODES) { int d = deg[idx]; row_ptr[idx] = run; cursor[idx] = run; run += d; }
  }
}

__global__ __launch_bounds__(256) void k_scatter(
    const int* __restrict__ g_row, const int* __restrict__ g_col,
    const float* __restrict__ g_val, int* __restrict__ cursor,
    int* __restrict__ col_s, float* __restrict__ val_s) {
  int e = blockIdx.x * 256 + threadIdx.x;
  if (e < NEDGES) {
    int r = g_row[e];
    int p = atomicAdd(&cursor[r], 1);
    col_s[p] = g_col[e];
    val_s[p] = g_val[e];
  }
}

// ---------------------------------------------------------------------------
// Tiled f32 GEMM: Y[n][c] = Xcat@W + b. 32-node x 128-col tile per block.
// KTOT=256: Xcat = [X0|X1]; KTOT=128: just X0.
// ---------------------------------------------------------------------------
template<int KTOT>
__global__ __launch_bounds__(256) void k_gemm(
    const float* __restrict__ X0, const float* __restrict__ X1,
    const float* __restrict__ W, const float* __restrict__ bias,
    float* __restrict__ Y)
{
  __shared__ __align__(16) float sX[32 * 260];
  __shared__ __align__(16) float sW[64 * 128];
  const int t  = threadIdx.x;
  const int r0 = blockIdx.x * 32;
  constexpr int KF4 = KTOT / 4;
  for (int f = t; f < 32 * KF4; f += 256) {
    int row = f / KF4;
    int col = (f % KF4) << 2;
    int n = r0 + row;
    float4 v = make_float4(0.f, 0.f, 0.f, 0.f);
    if (n < NNODES) {
      if (col < 128) v = *(const float4*)&X0[(size_t)n * 128 + col];
      else           v = *(const float4*)&X1[(size_t)n * 128 + col - 128];
    }
    *(float4*)&sX[row * 260 + col] = v;
  }
  const int rg = (t >> 4) * 2;     // node pair within tile: 0,2,..,30
  const int c0 = (t & 15) * 4;     // cols c0..c0+3 and c0+64..c0+67
  const int c1 = c0 + 64;
  float acc[2][8];
  #pragma unroll
  for (int j = 0; j < 8; ++j) { acc[0][j] = 0.f; acc[1][j] = 0.f; }

  for (int kc = 0; kc < KTOT; kc += 64) {
    __syncthreads();
    for (int f = t; f < 2048; f += 256) {  // 64 k-rows * 32 float4
      int row = f >> 5, col = (f & 31) << 2;
      *(float4*)&sW[row * 128 + col] = *(const float4*)&W[(size_t)(kc + row) * 128 + col];
    }
    __syncthreads();
    #pragma unroll 8
    for (int k = 0; k < 64; ++k) {
      float x0 = sX[rg * 260 + kc + k];
      float x1 = sX[(rg + 1) * 260 + kc + k];
      float4 w0 = *(const float4*)&sW[k * 128 + c0];
      float4 w1 = *(const float4*)&sW[k * 128 + c1];
      acc[0][0] += x0*w0.x; acc[0][1] += x0*w0.y; acc[0][2] += x0*w0.z; acc[0][3] += x0*w0.w;
      acc[0][4] += x0*w1.x; acc[0][5] += x0*w1.y; acc[0][6] += x0*w1.z; acc[0][7] += x0*w1.w;
      acc[1][0] += x1*w0.x; acc[1][1] += x1*w0.y; acc[1][2] += x1*w0.z; acc[1][3] += x1*w0.w;
      acc[1][4] += x1*w1.x; acc[1][5] += x1*w1.y; acc[1][6] += x1*w1.z; acc[1][7] += x1*w1.w;
    }
  }
  float4 bv0 = *(const float4*)&bias[c0];
  float4 bv1 = *(const float4*)&bias[c1];
  #pragma unroll
  for (int i = 0; i < 2; ++i) {
    int n = r0 + rg + i;
    if (n < NNODES) {
      float4 o0 = make_float4(acc[i][0]+bv0.x, acc[i][1]+bv0.y, acc[i][2]+bv0.z, acc[i][3]+bv0.w);
      float4 o1 = make_float4(acc[i][4]+bv1.x, acc[i][5]+bv1.y, acc[i][6]+bv1.z, acc[i][7]+bv1.w);
      *(float4*)&Y[(size_t)n * 128 + c0] = o0;
      *(float4*)&Y[(size_t)n * 128 + c1] = o1;
    }
  }
}

// ---------------------------------------------------------------------------
// SpMM via CSR: wave per row, 2 feats/lane, no atomics.
// ---------------------------------------------------------------------------
__global__ __launch_bounds__(256) void k_spmm(
    const int* __restrict__ row_ptr, const int* __restrict__ col_s,
    const float* __restrict__ val_s, const float* __restrict__ X,
    float* __restrict__ Y)
{
  int w = (int)((blockIdx.x * 256u + threadIdx.x) >> 6);
  int lane = threadIdx.x & 63;
  if (w >= NNODES) return;
  int s = row_ptr[w], e = row_ptr[w + 1];
  int f = lane * 2;
  float ax = 0.f, ay = 0.f;
  for (int i = s; i < e; ++i) {
    int c = col_s[i];
    float v = val_s[i];
    float2 xv = *(const float2*)&X[(size_t)c * 128 + f];
    ax += v * xv.x; ay += v * xv.y;
  }
  float2 o; o.x = ax; o.y = ay;
  *(float2*)&Y[(size_t)w * 128 + f] = o;
}

// ---------------------------------------------------------------------------
// Gather with fused l2norm; f32 output. Wave per output row.
// ---------------------------------------------------------------------------
__global__ __launch_bounds__(256) void k_gather(
    const float* __restrict__ s1, const float* __restrict__ s2,
    const int* __restrict__ i0, const int* __restrict__ i1,
    const int* __restrict__ i2, const int* __restrict__ i3,
    float* __restrict__ out)
{
  long gw = ((long)blockIdx.x * 256 + threadIdx.x) >> 6;   // 0..799999
  int lane = threadIdx.x & 63;
  int o   = (int)(gw / 200000);
  int rem = (int)(gw % 200000);
  int l = rem / 100000;
  int i = rem % 100000;
  const int* idx = (o == 0) ? i0 : (o == 1) ? i1 : (o == 2) ? i2 : i3;
  int node = idx[i];
  const float* src = (l == 0) ? s1 : s2;
  float2 v = *(const float2*)&src[(size_t)node * 128 + lane * 2];
  float ss = v.x * v.x + v.y * v.y;
  for (int off = 32; off; off >>= 1) ss += __shfl_xor(ss, off, 64);
  float inv = 1.0f / fmaxf(sqrtf(ss), 1e-12f);
  float2 ov; ov.x = v.x * inv; ov.y = v.y * inv;
  *(float2*)&out[gw * 128 + lane * 2] = ov;
}

__global__ void k_loss_final(const float* __restrict__ loss_acc, float* __restrict__ out) {
  if (threadIdx.x == 0)
    out[102400000] = loss_acc[0] * (1.0f / 50000000.0f);
}

// ---------------------------------------------------------------------------
extern "C" void kernel_launch(void* const* d_in, const int* in_sizes, int n_in,
                              void* d_out, int out_size, void* d_ws, size_t ws_size,
                              hipStream_t stream)
{
  const float* emb_attr = (const float*)d_in[0];
  const float* emb_node = (const float*)d_in[1];
  const float* W0 = (const float*)d_in[2];
  const float* b0 = (const float*)d_in[3];
  const float* W1 = (const float*)d_in[4];
  const float* b1 = (const float*)d_in[5];
  const float* H  = (const float*)d_in[6];
  const float* g_val = (const float*)d_in[7];
  const int* g_row = (const int*)d_in[8];
  const int* g_col = (const int*)d_in[9];
  const int* pos_src = (const int*)d_in[10];
  const int* pos_dst = (const int*)d_in[11];
  const int* neg_src = (const int*)d_in[12];
  const int* neg_dst = (const int*)d_in[13];
  float* out = (float*)d_out;     // output dtype is float32

  const size_t NF = 12800000;

  // d_out (409.6 MB) doubles as scratch; gather + loss_final overwrite all of
  // it at the end. Layout (f32 units):
  float* F = (float*)d_out;
  float* Hacc     = F;                          // 12.8M
  float* y        = F + NF;                     // 12.8M
  int*   iw       = (int*)(F + 2 * NF);
  int*   row_ptr  = iw;                         // 100004
  int*   deg      = row_ptr + 100004;           // 100000
  int*   cursor   = deg + 100000;               // 100000
  int*   hrow_ptr = cursor + 100000;            // 100004
  int*   hcnt     = hrow_ptr + 100004;          // 100000
  int*   hcursor  = hcnt + 100000;              // 100000
  int*   col_s    = hcursor + 100000;           // 3.2M
  int*   hattr    = col_s + 3200000;            // 8M
  float* val_s    = (float*)(hattr + HCAP);     // 3.2M  (ends ~40.6M f32)

  float* s1 = (float*)d_ws;                     // 12.8M f32
  float* s2 = s1 + NF;                          // 12.8M f32
  float* loss_acc = s2 + NF;                    // 4

  hipMemsetAsync(loss_acc, 0, 16, stream);
  hipMemsetAsync(deg, 0, NNODES * sizeof(int), stream);
  hipMemsetAsync(hcnt, 0, NNODES * sizeof(int), stream);

  // --- sparse Hacc = H^T @ emb_attr ---
  dim3 hgrid((NNODES + 1023) / 1024, NATTRI);
  k_hnz_count<<<hgrid, 256, 0, stream>>>(H, hcnt);
  k_scan<<<1, 256, 0, stream>>>(hcnt, hrow_ptr, hcursor);
  k_hnz_place<<<hgrid, 256, 0, stream>>>(H, hcursor, hattr);
  k_hacc_sparse<<<NNODES / 4, 256, 0, stream>>>(hrow_ptr, hattr, emb_attr, Hacc);

  // --- loss ---
  k_loss<<<(NNODES + 63) / 64, 256, 0, stream>>>(emb_attr, emb_node, H, loss_acc);

  // --- edge CSR ---
  k_hist<<<(NEDGES + 255) / 256, 256, 0, stream>>>(g_row, deg);
  k_scan<<<1, 256, 0, stream>>>(deg, row_ptr, cursor);
  k_scatter<<<(NEDGES + 255) / 256, 256, 0, stream>>>(g_row, g_col, g_val, cursor, col_s, val_s);

  // --- GNN layers ---
  k_gemm<256><<<(NNODES + 31) / 32, 256, 0, stream>>>(emb_node, Hacc, W0, b0, y);
  k_spmm<<<(NNODES * 64) / 256, 256, 0, stream>>>(row_ptr, col_s, val_s, y, s1);
  k_gemm<128><<<(NNODES + 31) / 32, 256, 0, stream>>>(s1, s1, W1, b1, y);
  k_spmm<<<(NNODES * 64) / 256, 256, 0, stream>>>(row_ptr, col_s, val_s, y, s2);

  // --- outputs ---
  k_gather<<<200000, 256, 0, stream>>>(s1, s2, pos_src, pos_dst, neg_src, neg_dst, out);
  k_loss_final<<<1, 64, 0, stream>>>(loss_acc, out);
}

// Round 8
// 2727.742 us; speedup vs baseline: 3.1290x; 1.3312x over previous
//
#include <hip/hip_runtime.h>
#include <hip/hip_bf16.h>

#define NFEAT   128
#define NATTRI  500
#define NNODES  100000
#define NEDGES  3200000
#define HCAP    8000000   // capacity of hattr list (expected ~500K nz)

typedef __hip_bfloat16 bf16;

__device__ __forceinline__ float sigmoidf_(float x) { return 1.0f / (1.0f + __expf(-x)); }

// ---------------------------------------------------------------------------
// H nonzero extraction, pass 1: per-node counts. Coalesced row-major H read.
// ---------------------------------------------------------------------------
__global__ __launch_bounds__(256) void k_hnz_count(
    const float* __restrict__ H, int* __restrict__ hcnt)
{
  const int a   = blockIdx.y;
  const int off = blockIdx.x * 1024 + threadIdx.x * 4;
  if (off + 3 < NNODES) {
    float4 h4 = *(const float4*)&H[(size_t)a * NNODES + off];
    if (h4.x > 0.5f) atomicAdd(&hcnt[off + 0], 1);
    if (h4.y > 0.5f) atomicAdd(&hcnt[off + 1], 1);
    if (h4.z > 0.5f) atomicAdd(&hcnt[off + 2], 1);
    if (h4.w > 0.5f) atomicAdd(&hcnt[off + 3], 1);
  } else {
    for (int j = 0; j < 4; ++j) {
      int n = off + j;
      if (n < NNODES && H[(size_t)a * NNODES + n] > 0.5f) atomicAdd(&hcnt[n], 1);
    }
  }
}

// ---------------------------------------------------------------------------
// H nonzero extraction, pass 2: place attr indices at cursor positions.
// ---------------------------------------------------------------------------
__global__ __launch_bounds__(256) void k_hnz_place(
    const float* __restrict__ H, int* __restrict__ hcursor,
    int* __restrict__ hattr)
{
  const int a   = blockIdx.y;
  const int off = blockIdx.x * 1024 + threadIdx.x * 4;
  if (off + 3 < NNODES) {
    float4 h4 = *(const float4*)&H[(size_t)a * NNODES + off];
    float hv[4] = {h4.x, h4.y, h4.z, h4.w};
    #pragma unroll
    for (int j = 0; j < 4; ++j) {
      if (hv[j] > 0.5f) {
        int pos = atomicAdd(&hcursor[off + j], 1);
        if (pos < HCAP) hattr[pos] = a;
      }
    }
  } else {
    for (int j = 0; j < 4; ++j) {
      int n = off + j;
      if (n < NNODES && H[(size_t)a * NNODES + n] > 0.5f) {
        int pos = atomicAdd(&hcursor[n], 1);
        if (pos < HCAP) hattr[pos] = a;
      }
    }
  }
}

// ---------------------------------------------------------------------------
// Hacc[n] = sum over nz attrs a of emb_attr[a]. Wave per node, 2 f/lane.
// ---------------------------------------------------------------------------
__global__ __launch_bounds__(256) void k_hacc_sparse(
    const int* __restrict__ hrow_ptr, const int* __restrict__ hattr,
    const float* __restrict__ emb_attr, float* __restrict__ Hacc)
{
  int n = blockIdx.x * 4 + (threadIdx.x >> 6);
  if (n >= NNODES) return;
  int lane = threadIdx.x & 63;
  int s = hrow_ptr[n], e = min(hrow_ptr[n + 1], HCAP);
  int f = lane * 2;
  float ax = 0.f, ay = 0.f;
  for (int i = s; i < e; ++i) {
    int a = hattr[i];                          // wave-uniform broadcast
    float2 v = *(const float2*)&emb_attr[a * 128 + f];
    ax += v.x; ay += v.y;
  }
  float2 o; o.x = ax; o.y = ay;
  *(float2*)&Hacc[(size_t)n * 128 + f] = o;
}

// ---------------------------------------------------------------------------
// Loss base term: sum over ALL (a,n) of 0.1*sigmoid(dot)^2. No H needed.
// Both operands staged in LDS; 64-node tile per block, 32-attr chunks.
// Mapping: a2=(t&15)*2 (16 attr-pairs), n4=(t>>4)*4 (16 node-quads)
//  -> sN reads are 16-lane broadcasts (conflict-free), sA reads <=4-way.
// ---------------------------------------------------------------------------
__global__ __launch_bounds__(256) void k_loss_base(
    const float* __restrict__ emb_attr,
    const float* __restrict__ emb_node,
    float* __restrict__ loss_acc)
{
  __shared__ __align__(16) float sN[64 * 132];
  __shared__ __align__(16) float sA[32 * 132];
  __shared__ float red[4];

  const int t  = threadIdx.x;
  const int n0 = blockIdx.x * 64;

  // stage node tile once: 64 rows x 32 float4
  for (int f = t; f < 2048; f += 256) {
    int row = f >> 5, col = (f & 31) << 2;
    int n = n0 + row;
    float4 v = make_float4(0.f, 0.f, 0.f, 0.f);
    if (n < NNODES) v = *(const float4*)&emb_node[(size_t)n * 128 + col];
    *(float4*)&sN[row * 132 + col] = v;
  }

  const int a2 = (t & 15) * 2;    // attr pair within chunk
  const int n4 = (t >> 4) * 4;    // node quad within tile
  const bool nvalid = (n0 + n4) < NNODES;   // NNODES%4==0 -> whole quad valid

  float lacc = 0.f;

  for (int c = 0; c < NATTRI; c += 32) {
    const int cnt = min(32, NATTRI - c);
    __syncthreads();                 // sN ready (first iter) / prev reads done
    for (int f = t; f < cnt * 32; f += 256) {
      int row = f >> 5, col = (f & 31) << 2;
      *(float4*)&sA[row * 132 + col] = *(const float4*)&emb_attr[(c + row) * 128 + col];
    }
    __syncthreads();

    if (a2 < cnt && nvalid) {
      float acc[2][4] = {{0.f,0.f,0.f,0.f},{0.f,0.f,0.f,0.f}};
      for (int k = 0; k < 128; k += 4) {
        float4 a0 = *(const float4*)&sA[a2 * 132 + k];
        float4 a1 = *(const float4*)&sA[(a2 + 1) * 132 + k];
        #pragma unroll
        for (int j = 0; j < 4; ++j) {
          float4 nv = *(const float4*)&sN[(n4 + j) * 132 + k];
          acc[0][j] += a0.x*nv.x + a0.y*nv.y + a0.z*nv.z + a0.w*nv.w;
          acc[1][j] += a1.x*nv.x + a1.y*nv.y + a1.z*nv.z + a1.w*nv.w;
        }
      }
      #pragma unroll
      for (int i = 0; i < 2; ++i) {
        #pragma unroll
        for (int j = 0; j < 4; ++j) {
          float s = sigmoidf_(acc[i][j]);
          lacc += 0.1f * s * s;
        }
      }
    }
  }
  float tot = lacc;
  for (int off = 32; off; off >>= 1) tot += __shfl_down(tot, off, 64);
  if ((t & 63) == 0) red[t >> 6] = tot;
  __syncthreads();
  if (t == 0) atomicAdd(loss_acc, red[0] + red[1] + red[2] + red[3]);
}

// ---------------------------------------------------------------------------
// Loss correction over H nonzeros: += 2(1-s)^2 - 0.1 s^2 per pos pair.
// Wave per node; dot via 2 f32/lane + wave reduce. ~5 nz/node avg.
// ---------------------------------------------------------------------------
__global__ __launch_bounds__(256) void k_loss_corr(
    const int* __restrict__ hrow_ptr, const int* __restrict__ hattr,
    const float* __restrict__ emb_attr, const float* __restrict__ emb_node,
    float* __restrict__ loss_acc)
{
  __shared__ float red[4];
  const int n = blockIdx.x * 4 + (threadIdx.x >> 6);
  const int lane = threadIdx.x & 63;
  float part = 0.f;
  if (n < NNODES) {
    int s = hrow_ptr[n], e = min(hrow_ptr[n + 1], HCAP);
    float2 x = *(const float2*)&emb_node[(size_t)n * 128 + lane * 2];
    for (int i = s; i < e; ++i) {
      int a = hattr[i];                        // wave-uniform
      float2 w = *(const float2*)&emb_attr[a * 128 + lane * 2];
      float d = x.x * w.x + x.y * w.y;
      for (int off = 32; off; off >>= 1) d += __shfl_xor(d, off, 64);
      if (lane == 0) {
        float sg = sigmoidf_(d);
        float om = 1.f - sg;
        part += 2.0f * om * om - 0.1f * sg * sg;
      }
    }
  }
  if (lane == 0) red[threadIdx.x >> 6] = part;
  __syncthreads();
  if (threadIdx.x == 0) atomicAdd(loss_acc, red[0] + red[1] + red[2] + red[3]);
}

// ---------------------------------------------------------------------------
// CSR build for the edge graph
// ---------------------------------------------------------------------------
__global__ __launch_bounds__(256) void k_hist(const int* __restrict__ g_row,
                                              int* __restrict__ deg) {
  int e = blockIdx.x * 256 + threadIdx.x;
  if (e < NEDGES) atomicAdd(&deg[g_row[e]], 1);
}

__global__ __launch_bounds__(256) void k_scan(const int* __restrict__ deg,
                                              int* __restrict__ row_ptr,
                                              int* __restrict__ cursor) {
  __shared__ int part[256];
  __shared__ int excl[257];
  const int t = threadIdx.x;
  const int CH = (NNODES + 255) / 256;
  int base = t * CH;
  int s = 0;
  for (int i = 0; i < CH; ++i) { int idx = base + i; if (idx < NNODES) s += deg[idx]; }
  part[t] = s;
  __syncthreads();
  if (t == 0) {
    int r = 0;
    for (int i = 0; i < 256; ++i) { excl[i] = r; r += part[i]; }
    excl[256] = r;
    row_ptr[NNODES] = r;
  }
  __syncthreads();
  int run = excl[t];
  for (int i = 0; i < CH; ++i) {
    int idx = base + i;
    if (idx < NNODES) { int d = deg[idx]; row_ptr[idx] = run; cursor[idx] = run; run += d; }
  }
}

__global__ __launch_bounds__(256) void k_scatter(
    const int* __restrict__ g_row, const int* __restrict__ g_col,
    const float* __restrict__ g_val, int* __restrict__ cursor,
    int* __restrict__ col_s, float* __restrict__ val_s) {
  int e = blockIdx.x * 256 + threadIdx.x;
  if (e < NEDGES) {
    int r = g_row[e];
    int p = atomicAdd(&cursor[r], 1);
    col_s[p] = g_col[e];
    val_s[p] = g_val[e];
  }
}

// ---------------------------------------------------------------------------
// Tiled f32 GEMM: Y[n][c] = Xcat@W + b. 32-node x 128-col tile per block.
// ---------------------------------------------------------------------------
template<int KTOT>
__global__ __launch_bounds__(256) void k_gemm(
    const float* __restrict__ X0, const float* __restrict__ X1,
    const float* __restrict__ W, const float* __restrict__ bias,
    float* __restrict__ Y)
{
  __shared__ __align__(16) float sX[32 * 260];
  __shared__ __align__(16) float sW[64 * 128];
  const int t  = threadIdx.x;
  const int r0 = blockIdx.x * 32;
  constexpr int KF4 = KTOT / 4;
  for (int f = t; f < 32 * KF4; f += 256) {
    int row = f / KF4;
    int col = (f % KF4) << 2;
    int n = r0 + row;
    float4 v = make_float4(0.f, 0.f, 0.f, 0.f);
    if (n < NNODES) {
      if (col < 128) v = *(const float4*)&X0[(size_t)n * 128 + col];
      else           v = *(const float4*)&X1[(size_t)n * 128 + col - 128];
    }
    *(float4*)&sX[row * 260 + col] = v;
  }
  const int rg = (t >> 4) * 2;
  const int c0 = (t & 15) * 4;
  const int c1 = c0 + 64;
  float acc[2][8];
  #pragma unroll
  for (int j = 0; j < 8; ++j) { acc[0][j] = 0.f; acc[1][j] = 0.f; }

  for (int kc = 0; kc < KTOT; kc += 64) {
    __syncthreads();
    for (int f = t; f < 2048; f += 256) {
      int row = f >> 5, col = (f & 31) << 2;
      *(float4*)&sW[row * 128 + col] = *(const float4*)&W[(size_t)(kc + row) * 128 + col];
    }
    __syncthreads();
    #pragma unroll 8
    for (int k = 0; k < 64; ++k) {
      float x0 = sX[rg * 260 + kc + k];
      float x1 = sX[(rg + 1) * 260 + kc + k];
      float4 w0 = *(const float4*)&sW[k * 128 + c0];
      float4 w1 = *(const float4*)&sW[k * 128 + c1];
      acc[0][0] += x0*w0.x; acc[0][1] += x0*w0.y; acc[0][2] += x0*w0.z; acc[0][3] += x0*w0.w;
      acc[0][4] += x0*w1.x; acc[0][5] += x0*w1.y; acc[0][6] += x0*w1.z; acc[0][7] += x0*w1.w;
      acc[1][0] += x1*w0.x; acc[1][1] += x1*w0.y; acc[1][2] += x1*w0.z; acc[1][3] += x1*w0.w;
      acc[1][4] += x1*w1.x; acc[1][5] += x1*w1.y; acc[1][6] += x1*w1.z; acc[1][7] += x1*w1.w;
    }
  }
  float4 bv0 = *(const float4*)&bias[c0];
  float4 bv1 = *(const float4*)&bias[c1];
  #pragma unroll
  for (int i = 0; i < 2; ++i) {
    int n = r0 + rg + i;
    if (n < NNODES) {
      float4 o0 = make_float4(acc[i][0]+bv0.x, acc[i][1]+bv0.y, acc[i][2]+bv0.z, acc[i][3]+bv0.w);
      float4 o1 = make_float4(acc[i][4]+bv1.x, acc[i][5]+bv1.y, acc[i][6]+bv1.z, acc[i][7]+bv1.w);
      *(float4*)&Y[(size_t)n * 128 + c0] = o0;
      *(float4*)&Y[(size_t)n * 128 + c1] = o1;
    }
  }
}

// ---------------------------------------------------------------------------
// SpMM via CSR: wave per row, 2 feats/lane, no atomics.
// ---------------------------------------------------------------------------
__global__ __launch_bounds__(256) void k_spmm(
    const int* __restrict__ row_ptr, const int* __restrict__ col_s,
    const float* __restrict__ val_s, const float* __restrict__ X,
    float* __restrict__ Y)
{
  int w = (int)((blockIdx.x * 256u + threadIdx.x) >> 6);
  int lane = threadIdx.x & 63;
  if (w >= NNODES) return;
  int s = row_ptr[w], e = row_ptr[w + 1];
  int f = lane * 2;
  float ax = 0.f, ay = 0.f;
  for (int i = s; i < e; ++i) {
    int c = col_s[i];
    float v = val_s[i];
    float2 xv = *(const float2*)&X[(size_t)c * 128 + f];
    ax += v * xv.x; ay += v * xv.y;
  }
  float2 o; o.x = ax; o.y = ay;
  *(float2*)&Y[(size_t)w * 128 + f] = o;
}

// ---------------------------------------------------------------------------
// Gather with fused l2norm; f32 output. Wave per output row.
// ---------------------------------------------------------------------------
__global__ __launch_bounds__(256) void k_gather(
    const float* __restrict__ s1, const float* __restrict__ s2,
    const int* __restrict__ i0, const int* __restrict__ i1,
    const int* __restrict__ i2, const int* __restrict__ i3,
    float* __restrict__ out)
{
  long gw = ((long)blockIdx.x * 256 + threadIdx.x) >> 6;   // 0..799999
  int lane = threadIdx.x & 63;
  int o   = (int)(gw / 200000);
  int rem = (int)(gw % 200000);
  int l = rem / 100000;
  int i = rem % 100000;
  const int* idx = (o == 0) ? i0 : (o == 1) ? i1 : (o == 2) ? i2 : i3;
  int node = idx[i];
  const float* src = (l == 0) ? s1 : s2;
  float2 v = *(const float2*)&src[(size_t)node * 128 + lane * 2];
  float ss = v.x * v.x + v.y * v.y;
  for (int off = 32; off; off >>= 1) ss += __shfl_xor(ss, off, 64);
  float inv = 1.0f / fmaxf(sqrtf(ss), 1e-12f);
  float2 ov; ov.x = v.x * inv; ov.y = v.y * inv;
  *(float2*)&out[gw * 128 + lane * 2] = ov;
}

__global__ void k_loss_final(const float* __restrict__ loss_acc, float* __restrict__ out) {
  if (threadIdx.x == 0)
    out[102400000] = loss_acc[0] * (1.0f / 50000000.0f);
}

// ---------------------------------------------------------------------------
extern "C" void kernel_launch(void* const* d_in, const int* in_sizes, int n_in,
                              void* d_out, int out_size, void* d_ws, size_t ws_size,
                              hipStream_t stream)
{
  const float* emb_attr = (const float*)d_in[0];
  const float* emb_node = (const float*)d_in[1];
  const float* W0 = (const float*)d_in[2];
  const float* b0 = (const float*)d_in[3];
  const float* W1 = (const float*)d_in[4];
  const float* b1 = (const float*)d_in[5];
  const float* H  = (const float*)d_in[6];
  const float* g_val = (const float*)d_in[7];
  const int* g_row = (const int*)d_in[8];
  const int* g_col = (const int*)d_in[9];
  const int* pos_src = (const int*)d_in[10];
  const int* pos_dst = (const int*)d_in[11];
  const int* neg_src = (const int*)d_in[12];
  const int* neg_dst = (const int*)d_in[13];
  float* out = (float*)d_out;     // output dtype is float32

  const size_t NF = 12800000;

  // d_out (409.6 MB) doubles as scratch; gather + loss_final overwrite all of
  // it at the end. Layout (f32 units):
  float* F = (float*)d_out;
  float* Hacc     = F;                          // 12.8M
  float* y        = F + NF;                     // 12.8M
  int*   iw       = (int*)(F + 2 * NF);
  int*   row_ptr  = iw;                         // 100004
  int*   deg      = row_ptr + 100004;           // 100000
  int*   cursor   = deg + 100000;               // 100000
  int*   hrow_ptr = cursor + 100000;            // 100004
  int*   hcnt     = hrow_ptr + 100004;          // 100000
  int*   hcursor  = hcnt + 100000;              // 100000
  int*   col_s    = hcursor + 100000;           // 3.2M
  int*   hattr    = col_s + 3200000;            // 8M
  float* val_s    = (float*)(hattr + HCAP);     // 3.2M  (ends ~40.6M f32)

  float* s1 = (float*)d_ws;                     // 12.8M f32
  float* s2 = s1 + NF;                          // 12.8M f32
  float* loss_acc = s2 + NF;                    // 4

  hipMemsetAsync(loss_acc, 0, 16, stream);
  hipMemsetAsync(deg, 0, NNODES * sizeof(int), stream);
  hipMemsetAsync(hcnt, 0, NNODES * sizeof(int), stream);

  // --- sparse H extraction (feeds Hacc AND loss correction) ---
  dim3 hgrid((NNODES + 1023) / 1024, NATTRI);
  k_hnz_count<<<hgrid, 256, 0, stream>>>(H, hcnt);
  k_scan<<<1, 256, 0, stream>>>(hcnt, hrow_ptr, hcursor);
  k_hnz_place<<<hgrid, 256, 0, stream>>>(H, hcursor, hattr);
  k_hacc_sparse<<<NNODES / 4, 256, 0, stream>>>(hrow_ptr, hattr, emb_attr, Hacc);

  // --- loss: dense base term (no H) + sparse correction ---
  k_loss_base<<<(NNODES + 63) / 64, 256, 0, stream>>>(emb_attr, emb_node, loss_acc);
  k_loss_corr<<<NNODES / 4, 256, 0, stream>>>(hrow_ptr, hattr, emb_attr, emb_node, loss_acc);

  // --- edge CSR ---
  k_hist<<<(NEDGES + 255) / 256, 256, 0, stream>>>(g_row, deg);
  k_scan<<<1, 256, 0, stream>>>(deg, row_ptr, cursor);
  k_scatter<<<(NEDGES + 255) / 256, 256, 0, stream>>>(g_row, g_col, g_val, cursor, col_s, val_s);

  // --- GNN layers ---
  k_gemm<256><<<(NNODES + 31) / 32, 256, 0, stream>>>(emb_node, Hacc, W0, b0, y);
  k_spmm<<<(NNODES * 64) / 256, 256, 0, stream>>>(row_ptr, col_s, val_s, y, s1);
  k_gemm<128><<<(NNODES + 31) / 32, 256, 0, stream>>>(s1, s1, W1, b1, y);
  k_spmm<<<(NNODES * 64) / 256, 256, 0, stream>>>(row_ptr, col_s, val_s, y, s2);

  // --- outputs ---
  k_gather<<<200000, 256, 0, stream>>>(s1, s2, pos_src, pos_dst, neg_src, neg_dst, out);
  k_loss_final<<<1, 64, 0, stream>>>(loss_acc, out);
}

// Round 9
// 2337.474 us; speedup vs baseline: 3.6515x; 1.1670x over previous
//
#include <hip/hip_runtime.h>
#include <hip/hip_bf16.h>

#define NFEAT   128
#define NATTRI  500
#define NNODES  100000
#define NEDGES  3200000
#define HCAP    8000000

typedef __hip_bfloat16 bf16;
typedef __attribute__((ext_vector_type(8))) short short8v;
typedef __attribute__((ext_vector_type(4))) float f32x4;

__device__ __forceinline__ float sigmoidf_(float x) { return 1.0f / (1.0f + __expf(-x)); }

// ---------------------------------------------------------------------------
// f32 -> bf16 cast, 4 elems/thread. n must be divisible by 4.
// ---------------------------------------------------------------------------
__global__ __launch_bounds__(256) void k_cvt_bf(const float* __restrict__ src,
                                                bf16* __restrict__ dst, int n)
{
  int i = (blockIdx.x * 256 + threadIdx.x) * 4;
  if (i >= n) return;
  float4 v = *(const float4*)&src[i];
  __hip_bfloat162 a, b;
  a.x = __float2bfloat16(v.x); a.y = __float2bfloat16(v.y);
  b.x = __float2bfloat16(v.z); b.y = __float2bfloat16(v.w);
  *(__hip_bfloat162*)&dst[i]     = a;
  *(__hip_bfloat162*)&dst[i + 2] = b;
}

// ---------------------------------------------------------------------------
// Small conversions: W0 -> W0t_bf [128][256], W1 -> W1t_bf [128][128],
// emb_attr -> attr_bf [500][128]. Grid covers 113152 exactly.
// ---------------------------------------------------------------------------
__global__ __launch_bounds__(256) void k_cvt_small(
    const float* __restrict__ W0, const float* __restrict__ W1,
    const float* __restrict__ emb_attr,
    bf16* __restrict__ W0t, bf16* __restrict__ W1t, bf16* __restrict__ attrb)
{
  int i = blockIdx.x * 256 + threadIdx.x;
  if (i < 32768) {                       // W0t[n][k] = W0[k][n], n<128,k<256
    int n = i >> 8, k = i & 255;
    W0t[i] = __float2bfloat16(W0[k * 128 + n]);
  } else if (i < 49152) {                // W1t[n][k] = W1[k][n], n<128,k<128
    int j = i - 32768;
    int n = j >> 7, k = j & 127;
    W1t[j] = __float2bfloat16(W1[k * 128 + n]);
  } else if (i < 113152) {               // attr_bf row-major copy
    int j = i - 49152;
    attrb[j] = __float2bfloat16(emb_attr[j]);
  }
}

// ---------------------------------------------------------------------------
// H nonzero extraction (unchanged)
// ---------------------------------------------------------------------------
__global__ __launch_bounds__(256) void k_hnz_count(
    const float* __restrict__ H, int* __restrict__ hcnt)
{
  const int a   = blockIdx.y;
  const int off = blockIdx.x * 1024 + threadIdx.x * 4;
  if (off + 3 < NNODES) {
    float4 h4 = *(const float4*)&H[(size_t)a * NNODES + off];
    if (h4.x > 0.5f) atomicAdd(&hcnt[off + 0], 1);
    if (h4.y > 0.5f) atomicAdd(&hcnt[off + 1], 1);
    if (h4.z > 0.5f) atomicAdd(&hcnt[off + 2], 1);
    if (h4.w > 0.5f) atomicAdd(&hcnt[off + 3], 1);
  } else {
    for (int j = 0; j < 4; ++j) {
      int n = off + j;
      if (n < NNODES && H[(size_t)a * NNODES + n] > 0.5f) atomicAdd(&hcnt[n], 1);
    }
  }
}

__global__ __launch_bounds__(256) void k_hnz_place(
    const float* __restrict__ H, int* __restrict__ hcursor,
    int* __restrict__ hattr)
{
  const int a   = blockIdx.y;
  const int off = blockIdx.x * 1024 + threadIdx.x * 4;
  if (off + 3 < NNODES) {
    float4 h4 = *(const float4*)&H[(size_t)a * NNODES + off];
    float hv[4] = {h4.x, h4.y, h4.z, h4.w};
    #pragma unroll
    for (int j = 0; j < 4; ++j) {
      if (hv[j] > 0.5f) {
        int pos = atomicAdd(&hcursor[off + j], 1);
        if (pos < HCAP) hattr[pos] = a;
      }
    }
  } else {
    for (int j = 0; j < 4; ++j) {
      int n = off + j;
      if (n < NNODES && H[(size_t)a * NNODES + n] > 0.5f) {
        int pos = atomicAdd(&hcursor[n], 1);
        if (pos < HCAP) hattr[pos] = a;
      }
    }
  }
}

// ---------------------------------------------------------------------------
// Hacc[n] = sum of emb_attr rows over H-nonzeros -> bf16 output.
// ---------------------------------------------------------------------------
__global__ __launch_bounds__(256) void k_hacc_sparse(
    const int* __restrict__ hrow_ptr, const int* __restrict__ hattr,
    const float* __restrict__ emb_attr, bf16* __restrict__ Haccb)
{
  int n = blockIdx.x * 4 + (threadIdx.x >> 6);
  if (n >= NNODES) return;
  int lane = threadIdx.x & 63;
  int s = hrow_ptr[n], e = min(hrow_ptr[n + 1], HCAP);
  int f = lane * 2;
  float ax = 0.f, ay = 0.f;
  for (int i = s; i < e; ++i) {
    int a = hattr[i];
    float2 v = *(const float2*)&emb_attr[a * 128 + f];
    ax += v.x; ay += v.y;
  }
  __hip_bfloat162 o;
  o.x = __float2bfloat16(ax); o.y = __float2bfloat16(ay);
  *(__hip_bfloat162*)&Haccb[(size_t)n * 128 + f] = o;
}

// ---------------------------------------------------------------------------
// MFMA GEMM: Y[n][c] = Xcat@W + b (f32 out). 128-row x 128-col tile/block.
// 4 waves, each 32 rows x 128 cols. K-chunks of 64 staged in LDS (stride 72).
// A-frag: lane holds A[l&15][(l>>4)*8+e]; B-frag: B[(l>>4)*8+e][l&15] via Wt.
// C/D: col=lane&15, row=(lane>>4)*4+reg  [m89 verified].
// ---------------------------------------------------------------------------
template<int KTOT>
__global__ __launch_bounds__(256) void k_gemm_mfma(
    const bf16* __restrict__ X0, const bf16* __restrict__ X1,
    const bf16* __restrict__ Wt,      // [128][KTOT] row-major
    const float* __restrict__ bias, float* __restrict__ Y)
{
  __shared__ __align__(16) short sX[128 * 72];
  __shared__ __align__(16) short sW[128 * 72];
  const int t = threadIdx.x;
  const int w = t >> 6, l = t & 63;
  const int lrow = l & 15, lk = (l >> 4) * 8;
  const int r0 = blockIdx.x * 128;

  f32x4 acc[2][8];
  #pragma unroll
  for (int m2 = 0; m2 < 2; ++m2)
    #pragma unroll
    for (int nf = 0; nf < 8; ++nf)
      acc[m2][nf] = (f32x4){0.f, 0.f, 0.f, 0.f};

  for (int kc = 0; kc < KTOT; kc += 64) {
    __syncthreads();
    {  // stage X tile: 128 rows x 64 k
      int row = t >> 1, ks = (t & 1) * 32;
      int n = r0 + row;
      int gk = kc + ks;
      const bf16* src = X0; int k0 = gk;
      if (KTOT == 256 && gk >= 128) { src = X1; k0 = gk - 128; }
      short* d = &sX[row * 72 + ks];
      if (n < NNODES) {
        const short* p = (const short*)&src[(size_t)n * 128 + k0];
        #pragma unroll
        for (int i = 0; i < 4; ++i) *(short8v*)&d[i * 8] = *(const short8v*)&p[i * 8];
      } else {
        short8v z = (short8v){0,0,0,0,0,0,0,0};
        #pragma unroll
        for (int i = 0; i < 4; ++i) *(short8v*)&d[i * 8] = z;
      }
    }
    {  // stage Wt tile: 128 n-rows x 64 k
      int nrow = t >> 1, ks = (t & 1) * 32;
      const short* p = (const short*)&Wt[(size_t)nrow * KTOT + kc + ks];
      short* d = &sW[nrow * 72 + ks];
      #pragma unroll
      for (int i = 0; i < 4; ++i) *(short8v*)&d[i * 8] = *(const short8v*)&p[i * 8];
    }
    __syncthreads();
    #pragma unroll
    for (int kf = 0; kf < 2; ++kf) {
      short8v a0 = *(const short8v*)&sX[(w * 32 +      lrow) * 72 + kf * 32 + lk];
      short8v a1 = *(const short8v*)&sX[(w * 32 + 16 + lrow) * 72 + kf * 32 + lk];
      #pragma unroll
      for (int nf = 0; nf < 8; ++nf) {
        short8v b = *(const short8v*)&sW[(nf * 16 + lrow) * 72 + kf * 32 + lk];
        acc[0][nf] = __builtin_amdgcn_mfma_f32_16x16x32_bf16(a0, b, acc[0][nf], 0, 0, 0);
        acc[1][nf] = __builtin_amdgcn_mfma_f32_16x16x32_bf16(a1, b, acc[1][nf], 0, 0, 0);
      }
    }
  }
  // epilogue: f32 + bias
  #pragma unroll
  for (int m2 = 0; m2 < 2; ++m2) {
    int rbase = r0 + w * 32 + m2 * 16 + (l >> 4) * 4;
    #pragma unroll
    for (int nf = 0; nf < 8; ++nf) {
      int col = nf * 16 + lrow;
      float bv = bias[col];
      #pragma unroll
      for (int ri = 0; ri < 4; ++ri) {
        int grow = rbase + ri;
        if (grow < NNODES) Y[(size_t)grow * 128 + col] = acc[m2][nf][ri] + bv;
      }
    }
  }
}

// ---------------------------------------------------------------------------
// MFMA loss base: sum 0.1*sigmoid(emb_node @ emb_attr^T)^2 over all pairs.
// Grid (node_tiles, 4 attr_tiles of 128, mask col<500).
// ---------------------------------------------------------------------------
__global__ __launch_bounds__(256) void k_loss_mfma(
    const bf16* __restrict__ Xb,      // embn_bf [NNODES][128]
    const bf16* __restrict__ Ab,      // attr_bf [500][128]
    float* __restrict__ loss_acc)
{
  __shared__ __align__(16) short sX[128 * 72];
  __shared__ __align__(16) short sW[128 * 72];
  __shared__ float red[4];
  const int t = threadIdx.x;
  const int w = t >> 6, l = t & 63;
  const int lrow = l & 15, lk = (l >> 4) * 8;
  const int r0 = blockIdx.x * 128;
  const int a0 = blockIdx.y * 128;

  f32x4 acc[2][8];
  #pragma unroll
  for (int m2 = 0; m2 < 2; ++m2)
    #pragma unroll
    for (int nf = 0; nf < 8; ++nf)
      acc[m2][nf] = (f32x4){0.f, 0.f, 0.f, 0.f};

  for (int kc = 0; kc < 128; kc += 64) {
    __syncthreads();
    {  // stage node tile
      int row = t >> 1, ks = (t & 1) * 32;
      int n = r0 + row;
      short* d = &sX[row * 72 + ks];
      if (n < NNODES) {
        const short* p = (const short*)&Xb[(size_t)n * 128 + kc + ks];
        #pragma unroll
        for (int i = 0; i < 4; ++i) *(short8v*)&d[i * 8] = *(const short8v*)&p[i * 8];
      } else {
        short8v z = (short8v){0,0,0,0,0,0,0,0};
        #pragma unroll
        for (int i = 0; i < 4; ++i) *(short8v*)&d[i * 8] = z;
      }
    }
    {  // stage attr tile
      int nrow = t >> 1, ks = (t & 1) * 32;
      int a = a0 + nrow;
      short* d = &sW[nrow * 72 + ks];
      if (a < NATTRI) {
        const short* p = (const short*)&Ab[(size_t)a * 128 + kc + ks];
        #pragma unroll
        for (int i = 0; i < 4; ++i) *(short8v*)&d[i * 8] = *(const short8v*)&p[i * 8];
      } else {
        short8v z = (short8v){0,0,0,0,0,0,0,0};
        #pragma unroll
        for (int i = 0; i < 4; ++i) *(short8v*)&d[i * 8] = z;
      }
    }
    __syncthreads();
    #pragma unroll
    for (int kf = 0; kf < 2; ++kf) {
      short8v av0 = *(const short8v*)&sX[(w * 32 +      lrow) * 72 + kf * 32 + lk];
      short8v av1 = *(const short8v*)&sX[(w * 32 + 16 + lrow) * 72 + kf * 32 + lk];
      #pragma unroll
      for (int nf = 0; nf < 8; ++nf) {
        short8v b = *(const short8v*)&sW[(nf * 16 + lrow) * 72 + kf * 32 + lk];
        acc[0][nf] = __builtin_amdgcn_mfma_f32_16x16x32_bf16(av0, b, acc[0][nf], 0, 0, 0);
        acc[1][nf] = __builtin_amdgcn_mfma_f32_16x16x32_bf16(av1, b, acc[1][nf], 0, 0, 0);
      }
    }
  }
  float lacc = 0.f;
  #pragma unroll
  for (int m2 = 0; m2 < 2; ++m2) {
    int rbase = r0 + w * 32 + m2 * 16 + (l >> 4) * 4;
    #pragma unroll
    for (int nf = 0; nf < 8; ++nf) {
      int col = a0 + nf * 16 + lrow;
      if (col < NATTRI) {
        #pragma unroll
        for (int ri = 0; ri < 4; ++ri) {
          int grow = rbase + ri;
          if (grow < NNODES) {
            float s = sigmoidf_(acc[m2][nf][ri]);
            lacc += 0.1f * s * s;
          }
        }
      }
    }
  }
  for (int off = 32; off; off >>= 1) lacc += __shfl_xor(lacc, off, 64);
  if (l == 0) red[w] = lacc;
  __syncthreads();
  if (t == 0) atomicAdd(loss_acc, red[0] + red[1] + red[2] + red[3]);
}

// ---------------------------------------------------------------------------
// Loss correction over H nonzeros (f32, unchanged).
// ---------------------------------------------------------------------------
__global__ __launch_bounds__(256) void k_loss_corr(
    const int* __restrict__ hrow_ptr, const int* __restrict__ hattr,
    const float* __restrict__ emb_attr, const float* __restrict__ emb_node,
    float* __restrict__ loss_acc)
{
  __shared__ float red[4];
  const int n = blockIdx.x * 4 + (threadIdx.x >> 6);
  const int lane = threadIdx.x & 63;
  float part = 0.f;
  if (n < NNODES) {
    int s = hrow_ptr[n], e = min(hrow_ptr[n + 1], HCAP);
    float2 x = *(const float2*)&emb_node[(size_t)n * 128 + lane * 2];
    for (int i = s; i < e; ++i) {
      int a = hattr[i];
      float2 wv = *(const float2*)&emb_attr[a * 128 + lane * 2];
      float d = x.x * wv.x + x.y * wv.y;
      for (int off = 32; off; off >>= 1) d += __shfl_xor(d, off, 64);
      if (lane == 0) {
        float sg = sigmoidf_(d);
        float om = 1.f - sg;
        part += 2.0f * om * om - 0.1f * sg * sg;
      }
    }
  }
  if (lane == 0) red[threadIdx.x >> 6] = part;
  __syncthreads();
  if (threadIdx.x == 0) atomicAdd(loss_acc, red[0] + red[1] + red[2] + red[3]);
}

// ---------------------------------------------------------------------------
// Edge CSR build (unchanged)
// ---------------------------------------------------------------------------
__global__ __launch_bounds__(256) void k_hist(const int* __restrict__ g_row,
                                              int* __restrict__ deg) {
  int e = blockIdx.x * 256 + threadIdx.x;
  if (e < NEDGES) atomicAdd(&deg[g_row[e]], 1);
}

__global__ __launch_bounds__(256) void k_scan(const int* __restrict__ deg,
                                              int* __restrict__ row_ptr,
                                              int* __restrict__ cursor) {
  __shared__ int part[256];
  __shared__ int excl[257];
  const int t = threadIdx.x;
  const int CH = (NNODES + 255) / 256;
  int base = t * CH;
  int s = 0;
  for (int i = 0; i < CH; ++i) { int idx = base + i; if (idx < NNODES) s += deg[idx]; }
  part[t] = s;
  __syncthreads();
  if (t == 0) {
    int r = 0;
    for (int i = 0; i < 256; ++i) { excl[i] = r; r += part[i]; }
    excl[256] = r;
    row_ptr[NNODES] = r;
  }
  __syncthreads();
  int run = excl[t];
  for (int i = 0; i < CH; ++i) {
    int idx = base + i;
    if (idx < NNODES) { int d = deg[idx]; row_ptr[idx] = run; cursor[idx] = run; run += d; }
  }
}

__global__ __launch_bounds__(256) void k_scatter(
    const int* __restrict__ g_row, const int* __restrict__ g_col,
    const float* __restrict__ g_val, int* __restrict__ cursor,
    int* __restrict__ col_s, float* __restrict__ val_s) {
  int e = blockIdx.x * 256 + threadIdx.x;
  if (e < NEDGES) {
    int r = g_row[e];
    int p = atomicAdd(&cursor[r], 1);
    col_s[p] = g_col[e];
    val_s[p] = g_val[e];
  }
}

// ---------------------------------------------------------------------------
// SpMM via CSR: wave per row, 2 feats/lane (f32, unchanged).
// ---------------------------------------------------------------------------
__global__ __launch_bounds__(256) void k_spmm(
    const int* __restrict__ row_ptr, const int* __restrict__ col_s,
    const float* __restrict__ val_s, const float* __restrict__ X,
    float* __restrict__ Y)
{
  int w = (int)((blockIdx.x * 256u + threadIdx.x) >> 6);
  int lane = threadIdx.x & 63;
  if (w >= NNODES) return;
  int s = row_ptr[w], e = row_ptr[w + 1];
  int f = lane * 2;
  float ax = 0.f, ay = 0.f;
  for (int i = s; i < e; ++i) {
    int c = col_s[i];
    float v = val_s[i];
    float2 xv = *(const float2*)&X[(size_t)c * 128 + f];
    ax += v * xv.x; ay += v * xv.y;
  }
  float2 o; o.x = ax; o.y = ay;
  *(float2*)&Y[(size_t)w * 128 + f] = o;
}

// ---------------------------------------------------------------------------
// Gather with fused l2norm; f32 output (unchanged).
// ---------------------------------------------------------------------------
__global__ __launch_bounds__(256) void k_gather(
    const float* __restrict__ s1, const float* __restrict__ s2,
    const int* __restrict__ i0, const int* __restrict__ i1,
    const int* __restrict__ i2, const int* __restrict__ i3,
    float* __restrict__ out)
{
  long gw = ((long)blockIdx.x * 256 + threadIdx.x) >> 6;
  int lane = threadIdx.x & 63;
  int o   = (int)(gw / 200000);
  int rem = (int)(gw % 200000);
  int l = rem / 100000;
  int i = rem % 100000;
  const int* idx = (o == 0) ? i0 : (o == 1) ? i1 : (o == 2) ? i2 : i3;
  int node = idx[i];
  const float* src = (l == 0) ? s1 : s2;
  float2 v = *(const float2*)&src[(size_t)node * 128 + lane * 2];
  float ss = v.x * v.x + v.y * v.y;
  for (int off = 32; off; off >>= 1) ss += __shfl_xor(ss, off, 64);
  float inv = 1.0f / fmaxf(sqrtf(ss), 1e-12f);
  float2 ov; ov.x = v.x * inv; ov.y = v.y * inv;
  *(float2*)&out[gw * 128 + lane * 2] = ov;
}

__global__ void k_loss_final(const float* __restrict__ loss_acc, float* __restrict__ out) {
  if (threadIdx.x == 0)
    out[102400000] = loss_acc[0] * (1.0f / 50000000.0f);
}

// ---------------------------------------------------------------------------
extern "C" void kernel_launch(void* const* d_in, const int* in_sizes, int n_in,
                              void* d_out, int out_size, void* d_ws, size_t ws_size,
                              hipStream_t stream)
{
  const float* emb_attr = (const float*)d_in[0];
  const float* emb_node = (const float*)d_in[1];
  const float* W0 = (const float*)d_in[2];
  const float* b0 = (const float*)d_in[3];
  const float* W1 = (const float*)d_in[4];
  const float* b1 = (const float*)d_in[5];
  const float* H  = (const float*)d_in[6];
  const float* g_val = (const float*)d_in[7];
  const int* g_row = (const int*)d_in[8];
  const int* g_col = (const int*)d_in[9];
  const int* pos_src = (const int*)d_in[10];
  const int* pos_dst = (const int*)d_in[11];
  const int* neg_src = (const int*)d_in[12];
  const int* neg_dst = (const int*)d_in[13];
  float* out = (float*)d_out;

  const size_t NF = 12800000;

  // d_out (409.6 MB) as scratch; all dead before the final gather overwrite.
  char* base = (char*)d_out;
  float* y       = (float*)base;                       // 51.2 MB f32
  bf16*  embn_bf = (bf16*)(base + 51200000);           // 25.6 MB
  bf16*  Hacc_bf = embn_bf + NF;                       // 25.6 MB
  bf16*  s1_bf   = Hacc_bf + NF;                       // 25.6 MB
  bf16*  W0t_bf  = s1_bf + NF;                         // 64 KB
  bf16*  W1t_bf  = W0t_bf + 32768;                     // 32 KB
  bf16*  attr_bf = W1t_bf + 16384;                     // 125 KB
  int*   row_ptr  = (int*)(attr_bf + 64000);
  int*   deg      = row_ptr + 100004;
  int*   cursor   = deg + 100000;
  int*   hrow_ptr = cursor + 100000;
  int*   hcnt     = hrow_ptr + 100004;
  int*   hcursor  = hcnt + 100000;
  int*   col_s    = hcursor + 100000;                  // 3.2M
  int*   hattr    = col_s + 3200000;                   // 8M
  float* val_s    = (float*)(hattr + HCAP);            // 3.2M (ends ~188MB)

  float* s1 = (float*)d_ws;                            // 51.2 MB
  float* s2 = s1 + NF;                                 // 51.2 MB
  float* loss_acc = s2 + NF;

  hipMemsetAsync(loss_acc, 0, 16, stream);
  hipMemsetAsync(deg, 0, NNODES * sizeof(int), stream);
  hipMemsetAsync(hcnt, 0, NNODES * sizeof(int), stream);

  // --- bf16 conversions ---
  k_cvt_bf<<<12500, 256, 0, stream>>>(emb_node, embn_bf, (int)NF);
  k_cvt_small<<<442, 256, 0, stream>>>(W0, W1, emb_attr, W0t_bf, W1t_bf, attr_bf);

  // --- sparse H extraction ---
  dim3 hgrid((NNODES + 1023) / 1024, NATTRI);
  k_hnz_count<<<hgrid, 256, 0, stream>>>(H, hcnt);
  k_scan<<<1, 256, 0, stream>>>(hcnt, hrow_ptr, hcursor);
  k_hnz_place<<<hgrid, 256, 0, stream>>>(H, hcursor, hattr);
  k_hacc_sparse<<<NNODES / 4, 256, 0, stream>>>(hrow_ptr, hattr, emb_attr, Hacc_bf);

  // --- loss: MFMA base term + sparse correction ---
  dim3 lgrid((NNODES + 127) / 128, 4);
  k_loss_mfma<<<lgrid, 256, 0, stream>>>(embn_bf, attr_bf, loss_acc);
  k_loss_corr<<<NNODES / 4, 256, 0, stream>>>(hrow_ptr, hattr, emb_attr, emb_node, loss_acc);

  // --- edge CSR ---
  k_hist<<<(NEDGES + 255) / 256, 256, 0, stream>>>(g_row, deg);
  k_scan<<<1, 256, 0, stream>>>(deg, row_ptr, cursor);
  k_scatter<<<(NEDGES + 255) / 256, 256, 0, stream>>>(g_row, g_col, g_val, cursor, col_s, val_s);

  // --- GNN layers (MFMA GEMMs) ---
  const int ggrid = (NNODES + 127) / 128;   // 782
  k_gemm_mfma<256><<<ggrid, 256, 0, stream>>>(embn_bf, Hacc_bf, W0t_bf, b0, y);
  k_spmm<<<(NNODES * 64) / 256, 256, 0, stream>>>(row_ptr, col_s, val_s, y, s1);
  k_cvt_bf<<<12500, 256, 0, stream>>>(s1, s1_bf, (int)NF);
  k_gemm_mfma<128><<<ggrid, 256, 0, stream>>>(s1_bf, (const bf16*)nullptr, W1t_bf, b1, y);
  k_spmm<<<(NNODES * 64) / 256, 256, 0, stream>>>(row_ptr, col_s, val_s, y, s2);

  // --- outputs ---
  k_gather<<<200000, 256, 0, stream>>>(s1, s2, pos_src, pos_dst, neg_src, neg_dst, out);
  k_loss_final<<<1, 64, 0, stream>>>(loss_acc, out);
}

// Round 10
// 2019.348 us; speedup vs baseline: 4.2267x; 1.1575x over previous
//
#include <hip/hip_runtime.h>
#include <hip/hip_bf16.h>

#define NFEAT   128
#define NATTRI  500
#define NNODES  100000
#define NEDGES  3200000
#define HCAP    1000000   // nz list capacity (expected ~500K, std ~700)

typedef __hip_bfloat16 bf16;
typedef __attribute__((ext_vector_type(8))) short short8v;
typedef __attribute__((ext_vector_type(4))) float f32x4;

__device__ __forceinline__ float sigmoidf_(float x) { return 1.0f / (1.0f + __expf(-x)); }

// ---------------------------------------------------------------------------
// f32 -> bf16 cast, 4 elems/thread.
// ---------------------------------------------------------------------------
__global__ __launch_bounds__(256) void k_cvt_bf(const float* __restrict__ src,
                                                bf16* __restrict__ dst, int n)
{
  int i = (blockIdx.x * 256 + threadIdx.x) * 4;
  if (i >= n) return;
  float4 v = *(const float4*)&src[i];
  __hip_bfloat162 a, b;
  a.x = __float2bfloat16(v.x); a.y = __float2bfloat16(v.y);
  b.x = __float2bfloat16(v.z); b.y = __float2bfloat16(v.w);
  *(__hip_bfloat162*)&dst[i]     = a;
  *(__hip_bfloat162*)&dst[i + 2] = b;
}

// ---------------------------------------------------------------------------
// Small conversions: W0t[128][256], W1t[128][128], attr_bf[500][128].
// ---------------------------------------------------------------------------
__global__ __launch_bounds__(256) void k_cvt_small(
    const float* __restrict__ W0, const float* __restrict__ W1,
    const float* __restrict__ emb_attr,
    bf16* __restrict__ W0t, bf16* __restrict__ W1t, bf16* __restrict__ attrb)
{
  int i = blockIdx.x * 256 + threadIdx.x;
  if (i < 32768) {
    int n = i >> 8, k = i & 255;
    W0t[i] = __float2bfloat16(W0[k * 128 + n]);
  } else if (i < 49152) {
    int j = i - 32768;
    int n = j >> 7, k = j & 127;
    W1t[j] = __float2bfloat16(W1[k * 128 + n]);
  } else if (i < 113152) {
    int j = i - 49152;
    attrb[j] = __float2bfloat16(emb_attr[j]);
  }
}

// ---------------------------------------------------------------------------
// H nonzero extraction
// ---------------------------------------------------------------------------
__global__ __launch_bounds__(256) void k_hnz_count(
    const float* __restrict__ H, int* __restrict__ hcnt)
{
  const int a   = blockIdx.y;
  const int off = blockIdx.x * 1024 + threadIdx.x * 4;
  if (off + 3 < NNODES) {
    float4 h4 = *(const float4*)&H[(size_t)a * NNODES + off];
    if (h4.x > 0.5f) atomicAdd(&hcnt[off + 0], 1);
    if (h4.y > 0.5f) atomicAdd(&hcnt[off + 1], 1);
    if (h4.z > 0.5f) atomicAdd(&hcnt[off + 2], 1);
    if (h4.w > 0.5f) atomicAdd(&hcnt[off + 3], 1);
  } else {
    for (int j = 0; j < 4; ++j) {
      int n = off + j;
      if (n < NNODES && H[(size_t)a * NNODES + n] > 0.5f) atomicAdd(&hcnt[n], 1);
    }
  }
}

__global__ __launch_bounds__(256) void k_hnz_place(
    const float* __restrict__ H, int* __restrict__ hcursor,
    int* __restrict__ hattr, int* __restrict__ hnode)
{
  const int a   = blockIdx.y;
  const int off = blockIdx.x * 1024 + threadIdx.x * 4;
  if (off + 3 < NNODES) {
    float4 h4 = *(const float4*)&H[(size_t)a * NNODES + off];
    float hv[4] = {h4.x, h4.y, h4.z, h4.w};
    #pragma unroll
    for (int j = 0; j < 4; ++j) {
      if (hv[j] > 0.5f) {
        int pos = atomicAdd(&hcursor[off + j], 1);
        if (pos < HCAP) { hattr[pos] = a; hnode[pos] = off + j; }
      }
    }
  } else {
    for (int j = 0; j < 4; ++j) {
      int n = off + j;
      if (n < NNODES && H[(size_t)a * NNODES + n] > 0.5f) {
        int pos = atomicAdd(&hcursor[n], 1);
        if (pos < HCAP) { hattr[pos] = a; hnode[pos] = n; }
      }
    }
  }
}

// ---------------------------------------------------------------------------
// Hacc[n] = sum of emb_attr rows over H-nonzeros -> bf16.
// ---------------------------------------------------------------------------
__global__ __launch_bounds__(256) void k_hacc_sparse(
    const int* __restrict__ hrow_ptr, const int* __restrict__ hattr,
    const float* __restrict__ emb_attr, bf16* __restrict__ Haccb)
{
  int n = blockIdx.x * 4 + (threadIdx.x >> 6);
  if (n >= NNODES) return;
  int lane = threadIdx.x & 63;
  int s = hrow_ptr[n], e = min(hrow_ptr[n + 1], HCAP);
  int f = lane * 2;
  float ax = 0.f, ay = 0.f;
  for (int i = s; i < e; ++i) {
    int a = hattr[i];
    float2 v = *(const float2*)&emb_attr[a * 128 + f];
    ax += v.x; ay += v.y;
  }
  __hip_bfloat162 o;
  o.x = __float2bfloat16(ax); o.y = __float2bfloat16(ay);
  *(__hip_bfloat162*)&Haccb[(size_t)n * 128 + f] = o;
}

// ---------------------------------------------------------------------------
// MFMA GEMM: Y[n][c] = Xcat@W + b, bf16 out. 128x128 tile, 4 waves.
// C/D: col=lane&15, row=(lane>>4)*4+reg  [m89 verified].
// ---------------------------------------------------------------------------
template<int KTOT>
__global__ __launch_bounds__(256) void k_gemm_mfma(
    const bf16* __restrict__ X0, const bf16* __restrict__ X1,
    const bf16* __restrict__ Wt,      // [128][KTOT] row-major
    const float* __restrict__ bias, bf16* __restrict__ Y)
{
  __shared__ __align__(16) short sX[128 * 72];
  __shared__ __align__(16) short sW[128 * 72];
  const int t = threadIdx.x;
  const int w = t >> 6, l = t & 63;
  const int lrow = l & 15, lk = (l >> 4) * 8;
  const int r0 = blockIdx.x * 128;

  f32x4 acc[2][8];
  #pragma unroll
  for (int m2 = 0; m2 < 2; ++m2)
    #pragma unroll
    for (int nf = 0; nf < 8; ++nf)
      acc[m2][nf] = (f32x4){0.f, 0.f, 0.f, 0.f};

  for (int kc = 0; kc < KTOT; kc += 64) {
    __syncthreads();
    {  // stage X tile: 128 rows x 64 k
      int row = t >> 1, ks = (t & 1) * 32;
      int n = r0 + row;
      int gk = kc + ks;
      const bf16* src = X0; int k0 = gk;
      if (KTOT == 256 && gk >= 128) { src = X1; k0 = gk - 128; }
      short* d = &sX[row * 72 + ks];
      if (n < NNODES) {
        const short* p = (const short*)&src[(size_t)n * 128 + k0];
        #pragma unroll
        for (int i = 0; i < 4; ++i) *(short8v*)&d[i * 8] = *(const short8v*)&p[i * 8];
      } else {
        short8v z = (short8v){0,0,0,0,0,0,0,0};
        #pragma unroll
        for (int i = 0; i < 4; ++i) *(short8v*)&d[i * 8] = z;
      }
    }
    {  // stage Wt tile
      int nrow = t >> 1, ks = (t & 1) * 32;
      const short* p = (const short*)&Wt[(size_t)nrow * KTOT + kc + ks];
      short* d = &sW[nrow * 72 + ks];
      #pragma unroll
      for (int i = 0; i < 4; ++i) *(short8v*)&d[i * 8] = *(const short8v*)&p[i * 8];
    }
    __syncthreads();
    #pragma unroll
    for (int kf = 0; kf < 2; ++kf) {
      short8v a0 = *(const short8v*)&sX[(w * 32 +      lrow) * 72 + kf * 32 + lk];
      short8v a1 = *(const short8v*)&sX[(w * 32 + 16 + lrow) * 72 + kf * 32 + lk];
      #pragma unroll
      for (int nf = 0; nf < 8; ++nf) {
        short8v b = *(const short8v*)&sW[(nf * 16 + lrow) * 72 + kf * 32 + lk];
        acc[0][nf] = __builtin_amdgcn_mfma_f32_16x16x32_bf16(a0, b, acc[0][nf], 0, 0, 0);
        acc[1][nf] = __builtin_amdgcn_mfma_f32_16x16x32_bf16(a1, b, acc[1][nf], 0, 0, 0);
      }
    }
  }
  #pragma unroll
  for (int m2 = 0; m2 < 2; ++m2) {
    int rbase = r0 + w * 32 + m2 * 16 + (l >> 4) * 4;
    #pragma unroll
    for (int nf = 0; nf < 8; ++nf) {
      int col = nf * 16 + lrow;
      float bv = bias[col];
      #pragma unroll
      for (int ri = 0; ri < 4; ++ri) {
        int grow = rbase + ri;
        if (grow < NNODES)
          Y[(size_t)grow * 128 + col] = __float2bfloat16(acc[m2][nf][ri] + bv);
      }
    }
  }
}

// ---------------------------------------------------------------------------
// MFMA loss base: sum 0.1*sigmoid(emb_node @ emb_attr^T)^2 over all pairs.
// ---------------------------------------------------------------------------
__global__ __launch_bounds__(256) void k_loss_mfma(
    const bf16* __restrict__ Xb, const bf16* __restrict__ Ab,
    float* __restrict__ loss_acc)
{
  __shared__ __align__(16) short sX[128 * 72];
  __shared__ __align__(16) short sW[128 * 72];
  __shared__ float red[4];
  const int t = threadIdx.x;
  const int w = t >> 6, l = t & 63;
  const int lrow = l & 15, lk = (l >> 4) * 8;
  const int r0 = blockIdx.x * 128;
  const int a0 = blockIdx.y * 128;

  f32x4 acc[2][8];
  #pragma unroll
  for (int m2 = 0; m2 < 2; ++m2)
    #pragma unroll
    for (int nf = 0; nf < 8; ++nf)
      acc[m2][nf] = (f32x4){0.f, 0.f, 0.f, 0.f};

  for (int kc = 0; kc < 128; kc += 64) {
    __syncthreads();
    {
      int row = t >> 1, ks = (t & 1) * 32;
      int n = r0 + row;
      short* d = &sX[row * 72 + ks];
      if (n < NNODES) {
        const short* p = (const short*)&Xb[(size_t)n * 128 + kc + ks];
        #pragma unroll
        for (int i = 0; i < 4; ++i) *(short8v*)&d[i * 8] = *(const short8v*)&p[i * 8];
      } else {
        short8v z = (short8v){0,0,0,0,0,0,0,0};
        #pragma unroll
        for (int i = 0; i < 4; ++i) *(short8v*)&d[i * 8] = z;
      }
    }
    {
      int nrow = t >> 1, ks = (t & 1) * 32;
      int a = a0 + nrow;
      short* d = &sW[nrow * 72 + ks];
      if (a < NATTRI) {
        const short* p = (const short*)&Ab[(size_t)a * 128 + kc + ks];
        #pragma unroll
        for (int i = 0; i < 4; ++i) *(short8v*)&d[i * 8] = *(const short8v*)&p[i * 8];
      } else {
        short8v z = (short8v){0,0,0,0,0,0,0,0};
        #pragma unroll
        for (int i = 0; i < 4; ++i) *(short8v*)&d[i * 8] = z;
      }
    }
    __syncthreads();
    #pragma unroll
    for (int kf = 0; kf < 2; ++kf) {
      short8v av0 = *(const short8v*)&sX[(w * 32 +      lrow) * 72 + kf * 32 + lk];
      short8v av1 = *(const short8v*)&sX[(w * 32 + 16 + lrow) * 72 + kf * 32 + lk];
      #pragma unroll
      for (int nf = 0; nf < 8; ++nf) {
        short8v b = *(const short8v*)&sW[(nf * 16 + lrow) * 72 + kf * 32 + lk];
        acc[0][nf] = __builtin_amdgcn_mfma_f32_16x16x32_bf16(av0, b, acc[0][nf], 0, 0, 0);
        acc[1][nf] = __builtin_amdgcn_mfma_f32_16x16x32_bf16(av1, b, acc[1][nf], 0, 0, 0);
      }
    }
  }
  float lacc = 0.f;
  #pragma unroll
  for (int m2 = 0; m2 < 2; ++m2) {
    int rbase = r0 + w * 32 + m2 * 16 + (l >> 4) * 4;
    #pragma unroll
    for (int nf = 0; nf < 8; ++nf) {
      int col = a0 + nf * 16 + lrow;
      if (col < NATTRI) {
        #pragma unroll
        for (int ri = 0; ri < 4; ++ri) {
          int grow = rbase + ri;
          if (grow < NNODES) {
            float s = sigmoidf_(acc[m2][nf][ri]);
            lacc += 0.1f * s * s;
          }
        }
      }
    }
  }
  for (int off = 32; off; off >>= 1) lacc += __shfl_xor(lacc, off, 64);
  if (l == 0) red[w] = lacc;
  __syncthreads();
  if (t == 0) atomicAdd(loss_acc, red[0] + red[1] + red[2] + red[3]);
}

// ---------------------------------------------------------------------------
// Flat loss correction: wave per nz entry, grid-stride. += 2(1-s)^2 - 0.1 s^2.
// ---------------------------------------------------------------------------
__global__ __launch_bounds__(256) void k_loss_corr_flat(
    const int* __restrict__ hnode, const int* __restrict__ hattr,
    const int* __restrict__ hrow_ptr,
    const float* __restrict__ emb_attr, const float* __restrict__ emb_node,
    float* __restrict__ loss_acc)
{
  __shared__ float red[4];
  const int total = min(hrow_ptr[NNODES], HCAP);
  const int lane = threadIdx.x & 63;
  const int wv = (blockIdx.x * 256 + threadIdx.x) >> 6;
  const int nw = gridDim.x * 4;
  float part = 0.f;
  for (int i = wv; i < total; i += nw) {
    int n = hnode[i];
    int a = hattr[i];
    float2 x = *(const float2*)&emb_node[(size_t)n * 128 + lane * 2];
    float2 w = *(const float2*)&emb_attr[a * 128 + lane * 2];
    float d = x.x * w.x + x.y * w.y;
    for (int off = 32; off; off >>= 1) d += __shfl_xor(d, off, 64);
    if (lane == 0) {
      float sg = sigmoidf_(d);
      float om = 1.f - sg;
      part += 2.0f * om * om - 0.1f * sg * sg;
    }
  }
  if (lane == 0) red[threadIdx.x >> 6] = part;
  __syncthreads();
  if (threadIdx.x == 0) atomicAdd(loss_acc, red[0] + red[1] + red[2] + red[3]);
}

// ---------------------------------------------------------------------------
// Edge CSR build
// ---------------------------------------------------------------------------
__global__ __launch_bounds__(256) void k_hist(const int* __restrict__ g_row,
                                              int* __restrict__ deg) {
  int e = blockIdx.x * 256 + threadIdx.x;
  if (e < NEDGES) atomicAdd(&deg[g_row[e]], 1);
}

__global__ __launch_bounds__(256) void k_scan(const int* __restrict__ deg,
                                              int* __restrict__ row_ptr,
                                              int* __restrict__ cursor) {
  __shared__ int part[256];
  __shared__ int excl[257];
  const int t = threadIdx.x;
  const int CH = (NNODES + 255) / 256;
  int base = t * CH;
  int s = 0;
  for (int i = 0; i < CH; ++i) { int idx = base + i; if (idx < NNODES) s += deg[idx]; }
  part[t] = s;
  __syncthreads();
  if (t == 0) {
    int r = 0;
    for (int i = 0; i < 256; ++i) { excl[i] = r; r += part[i]; }
    excl[256] = r;
    row_ptr[NNODES] = r;
  }
  __syncthreads();
  int run = excl[t];
  for (int i = 0; i < CH; ++i) {
    int idx = base + i;
    if (idx < NNODES) { int d = deg[idx]; row_ptr[idx] = run; cursor[idx] = run; run += d; }
  }
}

__global__ __launch_bounds__(256) void k_scatter(
    const int* __restrict__ g_row, const int* __restrict__ g_col,
    const float* __restrict__ g_val, int* __restrict__ cursor,
    int* __restrict__ col_s, float* __restrict__ val_s) {
  int e = blockIdx.x * 256 + threadIdx.x;
  if (e < NEDGES) {
    int r = g_row[e];
    int p = atomicAdd(&cursor[r], 1);
    col_s[p] = g_col[e];
    val_s[p] = g_val[e];
  }
}

// ---------------------------------------------------------------------------
// SpMM via CSR: wave per row, 2 feats/lane. Reads bf16 X, f32 accumulate.
// Writes f32 Y; if WRITE_BF also writes bf16 Yb (for next GEMM).
// ---------------------------------------------------------------------------
template<bool WRITE_BF>
__global__ __launch_bounds__(256) void k_spmm(
    const int* __restrict__ row_ptr, const int* __restrict__ col_s,
    const float* __restrict__ val_s, const bf16* __restrict__ X,
    float* __restrict__ Y, bf16* __restrict__ Yb)
{
  int w = (int)((blockIdx.x * 256u + threadIdx.x) >> 6);
  int lane = threadIdx.x & 63;
  if (w >= NNODES) return;
  int s = row_ptr[w], e = row_ptr[w + 1];
  int f = lane * 2;
  float ax = 0.f, ay = 0.f;
  for (int i = s; i < e; ++i) {
    int c = col_s[i];
    float v = val_s[i];
    __hip_bfloat162 xv = *(const __hip_bfloat162*)&X[(size_t)c * 128 + f];
    ax += v * __bfloat162float(xv.x);
    ay += v * __bfloat162float(xv.y);
  }
  float2 o; o.x = ax; o.y = ay;
  *(float2*)&Y[(size_t)w * 128 + f] = o;
  if (WRITE_BF) {
    __hip_bfloat162 ob;
    ob.x = __float2bfloat16(ax); ob.y = __float2bfloat16(ay);
    *(__hip_bfloat162*)&Yb[(size_t)w * 128 + f] = ob;
  }
}

// ---------------------------------------------------------------------------
// Gather with fused l2norm; f32 output.
// ---------------------------------------------------------------------------
__global__ __launch_bounds__(256) void k_gather(
    const float* __restrict__ s1, const float* __restrict__ s2,
    const int* __restrict__ i0, const int* __restrict__ i1,
    const int* __restrict__ i2, const int* __restrict__ i3,
    float* __restrict__ out)
{
  long gw = ((long)blockIdx.x * 256 + threadIdx.x) >> 6;
  int lane = threadIdx.x & 63;
  int o   = (int)(gw / 200000);
  int rem = (int)(gw % 200000);
  int l = rem / 100000;
  int i = rem % 100000;
  const int* idx = (o == 0) ? i0 : (o == 1) ? i1 : (o == 2) ? i2 : i3;
  int node = idx[i];
  const float* src = (l == 0) ? s1 : s2;
  float2 v = *(const float2*)&src[(size_t)node * 128 + lane * 2];
  float ss = v.x * v.x + v.y * v.y;
  for (int off = 32; off; off >>= 1) ss += __shfl_xor(ss, off, 64);
  float inv = 1.0f / fmaxf(sqrtf(ss), 1e-12f);
  float2 ov; ov.x = v.x * inv; ov.y = v.y * inv;
  *(float2*)&out[gw * 128 + lane * 2] = ov;
}

__global__ void k_loss_final(const float* __restrict__ loss_acc, float* __restrict__ out) {
  if (threadIdx.x == 0)
    out[102400000] = loss_acc[0] * (1.0f / 50000000.0f);
}

// ---------------------------------------------------------------------------
extern "C" void kernel_launch(void* const* d_in, const int* in_sizes, int n_in,
                              void* d_out, int out_size, void* d_ws, size_t ws_size,
                              hipStream_t stream)
{
  const float* emb_attr = (const float*)d_in[0];
  const float* emb_node = (const float*)d_in[1];
  const float* W0 = (const float*)d_in[2];
  const float* b0 = (const float*)d_in[3];
  const float* W1 = (const float*)d_in[4];
  const float* b1 = (const float*)d_in[5];
  const float* H  = (const float*)d_in[6];
  const float* g_val = (const float*)d_in[7];
  const int* g_row = (const int*)d_in[8];
  const int* g_col = (const int*)d_in[9];
  const int* pos_src = (const int*)d_in[10];
  const int* pos_dst = (const int*)d_in[11];
  const int* neg_src = (const int*)d_in[12];
  const int* neg_dst = (const int*)d_in[13];
  float* out = (float*)d_out;

  const size_t NF = 12800000;

  // d_out (409.6 MB) as scratch; all dead before the final gather overwrite.
  char* base = (char*)d_out;
  bf16*  embn_bf = (bf16*)base;                        // 25.6 MB
  bf16*  Hacc_bf = embn_bf + NF;                       // 25.6 MB
  bf16*  y_bf    = Hacc_bf + NF;                       // 25.6 MB
  bf16*  s1_bf   = y_bf + NF;                          // 25.6 MB
  bf16*  W0t_bf  = s1_bf + NF;                         // 64 KB
  bf16*  W1t_bf  = W0t_bf + 32768;                     // 32 KB
  bf16*  attr_bf = W1t_bf + 16384;                     // 125 KB
  int*   row_ptr  = (int*)(attr_bf + 64000);
  int*   deg      = row_ptr + 100004;
  int*   cursor   = deg + 100000;
  int*   hrow_ptr = cursor + 100000;
  int*   hcnt     = hrow_ptr + 100004;
  int*   hcursor  = hcnt + 100000;
  int*   col_s    = hcursor + 100000;                  // 3.2M
  int*   hattr    = col_s + 3200000;                   // 1M
  int*   hnode    = hattr + HCAP;                      // 1M
  float* val_s    = (float*)(hnode + HCAP);            // 3.2M

  float* s1 = (float*)d_ws;                            // 51.2 MB
  float* s2 = s1 + NF;                                 // 51.2 MB
  float* loss_acc = s2 + NF;

  hipMemsetAsync(loss_acc, 0, 16, stream);
  hipMemsetAsync(deg, 0, NNODES * sizeof(int), stream);
  hipMemsetAsync(hcnt, 0, NNODES * sizeof(int), stream);

  // --- bf16 conversions ---
  k_cvt_bf<<<12500, 256, 0, stream>>>(emb_node, embn_bf, (int)NF);
  k_cvt_small<<<442, 256, 0, stream>>>(W0, W1, emb_attr, W0t_bf, W1t_bf, attr_bf);

  // --- sparse H extraction ---
  dim3 hgrid((NNODES + 1023) / 1024, NATTRI);
  k_hnz_count<<<hgrid, 256, 0, stream>>>(H, hcnt);
  k_scan<<<1, 256, 0, stream>>>(hcnt, hrow_ptr, hcursor);
  k_hnz_place<<<hgrid, 256, 0, stream>>>(H, hcursor, hattr, hnode);
  k_hacc_sparse<<<NNODES / 4, 256, 0, stream>>>(hrow_ptr, hattr, emb_attr, Hacc_bf);

  // --- loss: MFMA base + flat sparse correction ---
  dim3 lgrid((NNODES + 127) / 128, 4);
  k_loss_mfma<<<lgrid, 256, 0, stream>>>(embn_bf, attr_bf, loss_acc);
  k_loss_corr_flat<<<4096, 256, 0, stream>>>(hnode, hattr, hrow_ptr, emb_attr, emb_node, loss_acc);

  // --- edge CSR ---
  k_hist<<<(NEDGES + 255) / 256, 256, 0, stream>>>(g_row, deg);
  k_scan<<<1, 256, 0, stream>>>(deg, row_ptr, cursor);
  k_scatter<<<(NEDGES + 255) / 256, 256, 0, stream>>>(g_row, g_col, g_val, cursor, col_s, val_s);

  // --- GNN layers ---
  const int ggrid = (NNODES + 127) / 128;   // 782
  k_gemm_mfma<256><<<ggrid, 256, 0, stream>>>(embn_bf, Hacc_bf, W0t_bf, b0, y_bf);
  k_spmm<true><<<(NNODES * 64) / 256, 256, 0, stream>>>(row_ptr, col_s, val_s, y_bf, s1, s1_bf);
  k_gemm_mfma<128><<<ggrid, 256, 0, stream>>>(s1_bf, (const bf16*)nullptr, W1t_bf, b1, y_bf);
  k_spmm<false><<<(NNODES * 64) / 256, 256, 0, stream>>>(row_ptr, col_s, val_s, y_bf, s2, (bf16*)nullptr);

  // --- outputs ---
  k_gather<<<200000, 256, 0, stream>>>(s1, s2, pos_src, pos_dst, neg_src, neg_dst, out);
  k_loss_final<<<1, 64, 0, stream>>>(loss_acc, out);
}

// Round 11
// 1470.975 us; speedup vs baseline: 5.8024x; 1.3728x over previous
//
#include <hip/hip_runtime.h>
#include <hip/hip_bf16.h>

#define NFEAT   128
#define NATTRI  500
#define NNODES  100000
#define NEDGES  3200000
#define HCAP    1000000   // nz list capacity (expected ~500K)

typedef __hip_bfloat16 bf16;
typedef __attribute__((ext_vector_type(8))) short short8v;
typedef __attribute__((ext_vector_type(4))) float f32x4;

__device__ __forceinline__ float sigmoidf_(float x) { return 1.0f / (1.0f + __expf(-x)); }

// ---------------------------------------------------------------------------
// f32 -> bf16 cast, 4 elems/thread.
// ---------------------------------------------------------------------------
__global__ __launch_bounds__(256) void k_cvt_bf(const float* __restrict__ src,
                                                bf16* __restrict__ dst, int n)
{
  int i = (blockIdx.x * 256 + threadIdx.x) * 4;
  if (i >= n) return;
  float4 v = *(const float4*)&src[i];
  __hip_bfloat162 a, b;
  a.x = __float2bfloat16(v.x); a.y = __float2bfloat16(v.y);
  b.x = __float2bfloat16(v.z); b.y = __float2bfloat16(v.w);
  *(__hip_bfloat162*)&dst[i]     = a;
  *(__hip_bfloat162*)&dst[i + 2] = b;
}

// ---------------------------------------------------------------------------
// Small conversions: W0t[128][256], W1t[128][128], attr_bf[500][128].
// ---------------------------------------------------------------------------
__global__ __launch_bounds__(256) void k_cvt_small(
    const float* __restrict__ W0, const float* __restrict__ W1,
    const float* __restrict__ emb_attr,
    bf16* __restrict__ W0t, bf16* __restrict__ W1t, bf16* __restrict__ attrb)
{
  int i = blockIdx.x * 256 + threadIdx.x;
  if (i < 32768) {
    int n = i >> 8, k = i & 255;
    W0t[i] = __float2bfloat16(W0[k * 128 + n]);
  } else if (i < 49152) {
    int j = i - 32768;
    int n = j >> 7, k = j & 127;
    W1t[j] = __float2bfloat16(W1[k * 128 + n]);
  } else if (i < 113152) {
    int j = i - 49152;
    attrb[j] = __float2bfloat16(emb_attr[j]);
  }
}

// ---------------------------------------------------------------------------
// H nonzero extraction
// ---------------------------------------------------------------------------
__global__ __launch_bounds__(256) void k_hnz_count(
    const float* __restrict__ H, int* __restrict__ hcnt)
{
  const int a   = blockIdx.y;
  const int off = blockIdx.x * 1024 + threadIdx.x * 4;
  if (off + 3 < NNODES) {
    float4 h4 = *(const float4*)&H[(size_t)a * NNODES + off];
    if (h4.x > 0.5f) atomicAdd(&hcnt[off + 0], 1);
    if (h4.y > 0.5f) atomicAdd(&hcnt[off + 1], 1);
    if (h4.z > 0.5f) atomicAdd(&hcnt[off + 2], 1);
    if (h4.w > 0.5f) atomicAdd(&hcnt[off + 3], 1);
  } else {
    for (int j = 0; j < 4; ++j) {
      int n = off + j;
      if (n < NNODES && H[(size_t)a * NNODES + n] > 0.5f) atomicAdd(&hcnt[n], 1);
    }
  }
}

__global__ __launch_bounds__(256) void k_hnz_place(
    const float* __restrict__ H, int* __restrict__ hcursor,
    int* __restrict__ hattr, int* __restrict__ hnode)
{
  const int a   = blockIdx.y;
  const int off = blockIdx.x * 1024 + threadIdx.x * 4;
  if (off + 3 < NNODES) {
    float4 h4 = *(const float4*)&H[(size_t)a * NNODES + off];
    float hv[4] = {h4.x, h4.y, h4.z, h4.w};
    #pragma unroll
    for (int j = 0; j < 4; ++j) {
      if (hv[j] > 0.5f) {
        int pos = atomicAdd(&hcursor[off + j], 1);
        if (pos < HCAP) { hattr[pos] = a; hnode[pos] = off + j; }
      }
    }
  } else {
    for (int j = 0; j < 4; ++j) {
      int n = off + j;
      if (n < NNODES && H[(size_t)a * NNODES + n] > 0.5f) {
        int pos = atomicAdd(&hcursor[n], 1);
        if (pos < HCAP) { hattr[pos] = a; hnode[pos] = n; }
      }
    }
  }
}

// ---------------------------------------------------------------------------
// Hacc[n] = sum of emb_attr rows over H-nonzeros -> bf16.
// ---------------------------------------------------------------------------
__global__ __launch_bounds__(256) void k_hacc_sparse(
    const int* __restrict__ hrow_ptr, const int* __restrict__ hattr,
    const float* __restrict__ emb_attr, bf16* __restrict__ Haccb)
{
  int n = blockIdx.x * 4 + (threadIdx.x >> 6);
  if (n >= NNODES) return;
  int lane = threadIdx.x & 63;
  int s = hrow_ptr[n], e = min(hrow_ptr[n + 1], HCAP);
  int f = lane * 2;
  float ax = 0.f, ay = 0.f;
  for (int i = s; i < e; ++i) {
    int a = hattr[i];
    float2 v = *(const float2*)&emb_attr[a * 128 + f];
    ax += v.x; ay += v.y;
  }
  __hip_bfloat162 o;
  o.x = __float2bfloat16(ax); o.y = __float2bfloat16(ay);
  *(__hip_bfloat162*)&Haccb[(size_t)n * 128 + f] = o;
}

// ---------------------------------------------------------------------------
// MFMA GEMM: Y[n][c] = Xcat@W + b, bf16 out. 128x128 tile, 4 waves.
// ---------------------------------------------------------------------------
template<int KTOT>
__global__ __launch_bounds__(256) void k_gemm_mfma(
    const bf16* __restrict__ X0, const bf16* __restrict__ X1,
    const bf16* __restrict__ Wt, const float* __restrict__ bias,
    bf16* __restrict__ Y)
{
  __shared__ __align__(16) short sX[128 * 72];
  __shared__ __align__(16) short sW[128 * 72];
  const int t = threadIdx.x;
  const int w = t >> 6, l = t & 63;
  const int lrow = l & 15, lk = (l >> 4) * 8;
  const int r0 = blockIdx.x * 128;

  f32x4 acc[2][8];
  #pragma unroll
  for (int m2 = 0; m2 < 2; ++m2)
    #pragma unroll
    for (int nf = 0; nf < 8; ++nf)
      acc[m2][nf] = (f32x4){0.f, 0.f, 0.f, 0.f};

  for (int kc = 0; kc < KTOT; kc += 64) {
    __syncthreads();
    {
      int row = t >> 1, ks = (t & 1) * 32;
      int n = r0 + row;
      int gk = kc + ks;
      const bf16* src = X0; int k0 = gk;
      if (KTOT == 256 && gk >= 128) { src = X1; k0 = gk - 128; }
      short* d = &sX[row * 72 + ks];
      if (n < NNODES) {
        const short* p = (const short*)&src[(size_t)n * 128 + k0];
        #pragma unroll
        for (int i = 0; i < 4; ++i) *(short8v*)&d[i * 8] = *(const short8v*)&p[i * 8];
      } else {
        short8v z = (short8v){0,0,0,0,0,0,0,0};
        #pragma unroll
        for (int i = 0; i < 4; ++i) *(short8v*)&d[i * 8] = z;
      }
    }
    {
      int nrow = t >> 1, ks = (t & 1) * 32;
      const short* p = (const short*)&Wt[(size_t)nrow * KTOT + kc + ks];
      short* d = &sW[nrow * 72 + ks];
      #pragma unroll
      for (int i = 0; i < 4; ++i) *(short8v*)&d[i * 8] = *(const short8v*)&p[i * 8];
    }
    __syncthreads();
    #pragma unroll
    for (int kf = 0; kf < 2; ++kf) {
      short8v a0 = *(const short8v*)&sX[(w * 32 +      lrow) * 72 + kf * 32 + lk];
      short8v a1 = *(const short8v*)&sX[(w * 32 + 16 + lrow) * 72 + kf * 32 + lk];
      #pragma unroll
      for (int nf = 0; nf < 8; ++nf) {
        short8v b = *(const short8v*)&sW[(nf * 16 + lrow) * 72 + kf * 32 + lk];
        acc[0][nf] = __builtin_amdgcn_mfma_f32_16x16x32_bf16(a0, b, acc[0][nf], 0, 0, 0);
        acc[1][nf] = __builtin_amdgcn_mfma_f32_16x16x32_bf16(a1, b, acc[1][nf], 0, 0, 0);
      }
    }
  }
  #pragma unroll
  for (int m2 = 0; m2 < 2; ++m2) {
    int rbase = r0 + w * 32 + m2 * 16 + (l >> 4) * 4;
    #pragma unroll
    for (int nf = 0; nf < 8; ++nf) {
      int col = nf * 16 + lrow;
      float bv = bias[col];
      #pragma unroll
      for (int ri = 0; ri < 4; ++ri) {
        int grow = rbase + ri;
        if (grow < NNODES)
          Y[(size_t)grow * 128 + col] = __float2bfloat16(acc[m2][nf][ri] + bv);
      }
    }
  }
}

// ---------------------------------------------------------------------------
// MFMA loss base: sum 0.1*sigmoid(emb_node @ emb_attr^T)^2 over all pairs.
// ---------------------------------------------------------------------------
__global__ __launch_bounds__(256) void k_loss_mfma(
    const bf16* __restrict__ Xb, const bf16* __restrict__ Ab,
    float* __restrict__ loss_acc)
{
  __shared__ __align__(16) short sX[128 * 72];
  __shared__ __align__(16) short sW[128 * 72];
  __shared__ float red[4];
  const int t = threadIdx.x;
  const int w = t >> 6, l = t & 63;
  const int lrow = l & 15, lk = (l >> 4) * 8;
  const int r0 = blockIdx.x * 128;
  const int a0 = blockIdx.y * 128;

  f32x4 acc[2][8];
  #pragma unroll
  for (int m2 = 0; m2 < 2; ++m2)
    #pragma unroll
    for (int nf = 0; nf < 8; ++nf)
      acc[m2][nf] = (f32x4){0.f, 0.f, 0.f, 0.f};

  for (int kc = 0; kc < 128; kc += 64) {
    __syncthreads();
    {
      int row = t >> 1, ks = (t & 1) * 32;
      int n = r0 + row;
      short* d = &sX[row * 72 + ks];
      if (n < NNODES) {
        const short* p = (const short*)&Xb[(size_t)n * 128 + kc + ks];
        #pragma unroll
        for (int i = 0; i < 4; ++i) *(short8v*)&d[i * 8] = *(const short8v*)&p[i * 8];
      } else {
        short8v z = (short8v){0,0,0,0,0,0,0,0};
        #pragma unroll
        for (int i = 0; i < 4; ++i) *(short8v*)&d[i * 8] = z;
      }
    }
    {
      int nrow = t >> 1, ks = (t & 1) * 32;
      int a = a0 + nrow;
      short* d = &sW[nrow * 72 + ks];
      if (a < NATTRI) {
        const short* p = (const short*)&Ab[(size_t)a * 128 + kc + ks];
        #pragma unroll
        for (int i = 0; i < 4; ++i) *(short8v*)&d[i * 8] = *(const short8v*)&p[i * 8];
      } else {
        short8v z = (short8v){0,0,0,0,0,0,0,0};
        #pragma unroll
        for (int i = 0; i < 4; ++i) *(short8v*)&d[i * 8] = z;
      }
    }
    __syncthreads();
    #pragma unroll
    for (int kf = 0; kf < 2; ++kf) {
      short8v av0 = *(const short8v*)&sX[(w * 32 +      lrow) * 72 + kf * 32 + lk];
      short8v av1 = *(const short8v*)&sX[(w * 32 + 16 + lrow) * 72 + kf * 32 + lk];
      #pragma unroll
      for (int nf = 0; nf < 8; ++nf) {
        short8v b = *(const short8v*)&sW[(nf * 16 + lrow) * 72 + kf * 32 + lk];
        acc[0][nf] = __builtin_amdgcn_mfma_f32_16x16x32_bf16(av0, b, acc[0][nf], 0, 0, 0);
        acc[1][nf] = __builtin_amdgcn_mfma_f32_16x16x32_bf16(av1, b, acc[1][nf], 0, 0, 0);
      }
    }
  }
  float lacc = 0.f;
  #pragma unroll
  for (int m2 = 0; m2 < 2; ++m2) {
    int rbase = r0 + w * 32 + m2 * 16 + (l >> 4) * 4;
    #pragma unroll
    for (int nf = 0; nf < 8; ++nf) {
      int col = a0 + nf * 16 + lrow;
      if (col < NATTRI) {
        #pragma unroll
        for (int ri = 0; ri < 4; ++ri) {
          int grow = rbase + ri;
          if (grow < NNODES) {
            float s = sigmoidf_(acc[m2][nf][ri]);
            lacc += 0.1f * s * s;
          }
        }
      }
    }
  }
  for (int off = 32; off; off >>= 1) lacc += __shfl_xor(lacc, off, 64);
  if (l == 0) red[w] = lacc;
  __syncthreads();
  if (t == 0) atomicAdd(loss_acc, red[0] + red[1] + red[2] + red[3]);
}

// ---------------------------------------------------------------------------
// Flat loss correction: wave per nz entry, grid-stride.
// ---------------------------------------------------------------------------
__global__ __launch_bounds__(256) void k_loss_corr_flat(
    const int* __restrict__ hnode, const int* __restrict__ hattr,
    const int* __restrict__ hrow_ptr,
    const float* __restrict__ emb_attr, const float* __restrict__ emb_node,
    float* __restrict__ loss_acc)
{
  __shared__ float red[4];
  const int total = min(hrow_ptr[NNODES], HCAP);
  const int lane = threadIdx.x & 63;
  const int wv = (blockIdx.x * 256 + threadIdx.x) >> 6;
  const int nw = gridDim.x * 4;
  float part = 0.f;
  for (int i = wv; i < total; i += nw) {
    int n = hnode[i];
    int a = hattr[i];
    float2 x = *(const float2*)&emb_node[(size_t)n * 128 + lane * 2];
    float2 w = *(const float2*)&emb_attr[a * 128 + lane * 2];
    float d = x.x * w.x + x.y * w.y;
    for (int off = 32; off; off >>= 1) d += __shfl_xor(d, off, 64);
    if (lane == 0) {
      float sg = sigmoidf_(d);
      float om = 1.f - sg;
      part += 2.0f * om * om - 0.1f * sg * sg;
    }
  }
  if (lane == 0) red[threadIdx.x >> 6] = part;
  __syncthreads();
  if (threadIdx.x == 0) atomicAdd(loss_acc, red[0] + red[1] + red[2] + red[3]);
}

// ---------------------------------------------------------------------------
// Edge CSR build: hist + 3-phase parallel scan + scatter
// ---------------------------------------------------------------------------
__global__ __launch_bounds__(256) void k_hist(const int* __restrict__ g_row,
                                              int* __restrict__ deg) {
  int e = blockIdx.x * 256 + threadIdx.x;
  if (e < NEDGES) atomicAdd(&deg[g_row[e]], 1);
}

// phase 1: 98 blocks, 1024 elems each -> bsum[98]
__global__ __launch_bounds__(256) void k_scan_p1(const int* __restrict__ deg,
                                                 int* __restrict__ bsum)
{
  __shared__ int wsum[4];
  int base = blockIdx.x * 1024 + threadIdx.x * 4;
  int s = 0;
  #pragma unroll
  for (int j = 0; j < 4; ++j) { int i = base + j; if (i < NNODES) s += deg[i]; }
  for (int off = 32; off; off >>= 1) s += __shfl_down(s, off, 64);
  if ((threadIdx.x & 63) == 0) wsum[threadIdx.x >> 6] = s;
  __syncthreads();
  if (threadIdx.x == 0) bsum[blockIdx.x] = wsum[0] + wsum[1] + wsum[2] + wsum[3];
}

// phase 2: 1 block, exclusive scan of NB block sums; writes row_ptr[NNODES]
__global__ void k_scan_p2(const int* __restrict__ bsum, int* __restrict__ boff,
                          int* __restrict__ row_ptr, int nb)
{
  __shared__ int tmp[128];
  int t = threadIdx.x;
  tmp[t] = (t < nb) ? bsum[t] : 0;
  __syncthreads();
  if (t == 0) {
    int r = 0;
    for (int i = 0; i < nb; ++i) { int v = tmp[i]; boff[i] = r; r += v; }
    row_ptr[NNODES] = r;
  }
}

// phase 3: per-block exclusive scan (Hillis-Steele over 256 thread sums)
__global__ __launch_bounds__(256) void k_scan_p3(
    const int* __restrict__ deg, const int* __restrict__ boff,
    int* __restrict__ row_ptr, int* __restrict__ cursor)
{
  __shared__ int tsum[256];
  const int t = threadIdx.x;
  int base = blockIdx.x * 1024 + t * 4;
  int v[4]; int s = 0;
  #pragma unroll
  for (int j = 0; j < 4; ++j) { int i = base + j; v[j] = (i < NNODES) ? deg[i] : 0; s += v[j]; }
  tsum[t] = s;
  __syncthreads();
  for (int off = 1; off < 256; off <<= 1) {
    int y = (t >= off) ? tsum[t - off] : 0;
    __syncthreads();
    tsum[t] += y;
    __syncthreads();
  }
  int run = boff[blockIdx.x] + tsum[t] - s;   // exclusive prefix
  #pragma unroll
  for (int j = 0; j < 4; ++j) {
    int i = base + j;
    if (i < NNODES) { row_ptr[i] = run; cursor[i] = run; run += v[j]; }
  }
}

__global__ __launch_bounds__(256) void k_scatter(
    const int* __restrict__ g_row, const int* __restrict__ g_col,
    const float* __restrict__ g_val, int* __restrict__ cursor,
    int* __restrict__ col_s, float* __restrict__ val_s) {
  int e = blockIdx.x * 256 + threadIdx.x;
  if (e < NEDGES) {
    int r = g_row[e];
    int p = atomicAdd(&cursor[r], 1);
    col_s[p] = g_col[e];
    val_s[p] = g_val[e];
  }
}

// ---------------------------------------------------------------------------
// SpMM via CSR: wave per row, 2 feats/lane. bf16 gather, f32 accumulate.
// ---------------------------------------------------------------------------
template<bool WRITE_BF>
__global__ __launch_bounds__(256) void k_spmm(
    const int* __restrict__ row_ptr, const int* __restrict__ col_s,
    const float* __restrict__ val_s, const bf16* __restrict__ X,
    float* __restrict__ Y, bf16* __restrict__ Yb)
{
  int w = (int)((blockIdx.x * 256u + threadIdx.x) >> 6);
  int lane = threadIdx.x & 63;
  if (w >= NNODES) return;
  int s = row_ptr[w], e = row_ptr[w + 1];
  int f = lane * 2;
  float ax = 0.f, ay = 0.f;
  for (int i = s; i < e; ++i) {
    int c = col_s[i];
    float v = val_s[i];
    __hip_bfloat162 xv = *(const __hip_bfloat162*)&X[(size_t)c * 128 + f];
    ax += v * __bfloat162float(xv.x);
    ay += v * __bfloat162float(xv.y);
  }
  float2 o; o.x = ax; o.y = ay;
  *(float2*)&Y[(size_t)w * 128 + f] = o;
  if (WRITE_BF) {
    __hip_bfloat162 ob;
    ob.x = __float2bfloat16(ax); ob.y = __float2bfloat16(ay);
    *(__hip_bfloat162*)&Yb[(size_t)w * 128 + f] = ob;
  }
}

// ---------------------------------------------------------------------------
// Gather with fused l2norm; f32 output.
// ---------------------------------------------------------------------------
__global__ __launch_bounds__(256) void k_gather(
    const float* __restrict__ s1, const float* __restrict__ s2,
    const int* __restrict__ i0, const int* __restrict__ i1,
    const int* __restrict__ i2, const int* __restrict__ i3,
    float* __restrict__ out)
{
  long gw = ((long)blockIdx.x * 256 + threadIdx.x) >> 6;
  int lane = threadIdx.x & 63;
  int o   = (int)(gw / 200000);
  int rem = (int)(gw % 200000);
  int l = rem / 100000;
  int i = rem % 100000;
  const int* idx = (o == 0) ? i0 : (o == 1) ? i1 : (o == 2) ? i2 : i3;
  int node = idx[i];
  const float* src = (l == 0) ? s1 : s2;
  float2 v = *(const float2*)&src[(size_t)node * 128 + lane * 2];
  float ss = v.x * v.x + v.y * v.y;
  for (int off = 32; off; off >>= 1) ss += __shfl_xor(ss, off, 64);
  float inv = 1.0f / fmaxf(sqrtf(ss), 1e-12f);
  float2 ov; ov.x = v.x * inv; ov.y = v.y * inv;
  *(float2*)&out[gw * 128 + lane * 2] = ov;
}

__global__ void k_loss_final(const float* __restrict__ loss_acc, float* __restrict__ out) {
  if (threadIdx.x == 0)
    out[102400000] = loss_acc[0] * (1.0f / 50000000.0f);
}

// ---------------------------------------------------------------------------
extern "C" void kernel_launch(void* const* d_in, const int* in_sizes, int n_in,
                              void* d_out, int out_size, void* d_ws, size_t ws_size,
                              hipStream_t stream)
{
  const float* emb_attr = (const float*)d_in[0];
  const float* emb_node = (const float*)d_in[1];
  const float* W0 = (const float*)d_in[2];
  const float* b0 = (const float*)d_in[3];
  const float* W1 = (const float*)d_in[4];
  const float* b1 = (const float*)d_in[5];
  const float* H  = (const float*)d_in[6];
  const float* g_val = (const float*)d_in[7];
  const int* g_row = (const int*)d_in[8];
  const int* g_col = (const int*)d_in[9];
  const int* pos_src = (const int*)d_in[10];
  const int* pos_dst = (const int*)d_in[11];
  const int* neg_src = (const int*)d_in[12];
  const int* neg_dst = (const int*)d_in[13];
  float* out = (float*)d_out;

  const size_t NF = 12800000;
  const int NB = (NNODES + 1023) / 1024;               // 98 scan blocks

  // d_out (409.6 MB) as scratch; all dead before the final gather overwrite.
  char* base = (char*)d_out;
  bf16*  embn_bf = (bf16*)base;                        // 25.6 MB
  bf16*  Hacc_bf = embn_bf + NF;                       // 25.6 MB
  bf16*  y_bf    = Hacc_bf + NF;                       // 25.6 MB
  bf16*  s1_bf   = y_bf + NF;                          // 25.6 MB
  bf16*  W0t_bf  = s1_bf + NF;                         // 64 KB
  bf16*  W1t_bf  = W0t_bf + 32768;                     // 32 KB
  bf16*  attr_bf = W1t_bf + 16384;                     // 125 KB
  int*   row_ptr  = (int*)(attr_bf + 64000);
  int*   deg      = row_ptr + 100004;
  int*   cursor   = deg + 100000;
  int*   hrow_ptr = cursor + 100000;
  int*   hcnt     = hrow_ptr + 100004;
  int*   hcursor  = hcnt + 100000;
  int*   bsum     = hcursor + 100000;                  // 128
  int*   boff     = bsum + 128;                        // 128
  int*   col_s    = boff + 128;                        // 3.2M
  int*   hattr    = col_s + 3200000;                   // 1M
  int*   hnode    = hattr + HCAP;                      // 1M
  float* val_s    = (float*)(hnode + HCAP);            // 3.2M

  float* s1 = (float*)d_ws;                            // 51.2 MB
  float* s2 = s1 + NF;                                 // 51.2 MB
  float* loss_acc = s2 + NF;

  hipMemsetAsync(loss_acc, 0, 16, stream);
  hipMemsetAsync(deg, 0, NNODES * sizeof(int), stream);
  hipMemsetAsync(hcnt, 0, NNODES * sizeof(int), stream);

  // --- bf16 conversions ---
  k_cvt_bf<<<12500, 256, 0, stream>>>(emb_node, embn_bf, (int)NF);
  k_cvt_small<<<442, 256, 0, stream>>>(W0, W1, emb_attr, W0t_bf, W1t_bf, attr_bf);

  // --- sparse H extraction ---
  dim3 hgrid(NB, NATTRI);
  k_hnz_count<<<hgrid, 256, 0, stream>>>(H, hcnt);
  k_scan_p1<<<NB, 256, 0, stream>>>(hcnt, bsum);
  k_scan_p2<<<1, 128, 0, stream>>>(bsum, boff, hrow_ptr, NB);
  k_scan_p3<<<NB, 256, 0, stream>>>(hcnt, boff, hrow_ptr, hcursor);
  k_hnz_place<<<hgrid, 256, 0, stream>>>(H, hcursor, hattr, hnode);
  k_hacc_sparse<<<NNODES / 4, 256, 0, stream>>>(hrow_ptr, hattr, emb_attr, Hacc_bf);

  // --- loss: MFMA base + flat sparse correction ---
  dim3 lgrid((NNODES + 127) / 128, 4);
  k_loss_mfma<<<lgrid, 256, 0, stream>>>(embn_bf, attr_bf, loss_acc);
  k_loss_corr_flat<<<4096, 256, 0, stream>>>(hnode, hattr, hrow_ptr, emb_attr, emb_node, loss_acc);

  // --- edge CSR ---
  k_hist<<<(NEDGES + 255) / 256, 256, 0, stream>>>(g_row, deg);
  k_scan_p1<<<NB, 256, 0, stream>>>(deg, bsum);
  k_scan_p2<<<1, 128, 0, stream>>>(bsum, boff, row_ptr, NB);
  k_scan_p3<<<NB, 256, 0, stream>>>(deg, boff, row_ptr, cursor);
  k_scatter<<<(NEDGES + 255) / 256, 256, 0, stream>>>(g_row, g_col, g_val, cursor, col_s, val_s);

  // --- GNN layers ---
  const int ggrid = (NNODES + 127) / 128;   // 782
  k_gemm_mfma<256><<<ggrid, 256, 0, stream>>>(embn_bf, Hacc_bf, W0t_bf, b0, y_bf);
  k_spmm<true><<<(NNODES * 64) / 256, 256, 0, stream>>>(row_ptr, col_s, val_s, y_bf, s1, s1_bf);
  k_gemm_mfma<128><<<ggrid, 256, 0, stream>>>(s1_bf, (const bf16*)nullptr, W1t_bf, b1, y_bf);
  k_spmm<false><<<(NNODES * 64) / 256, 256, 0, stream>>>(row_ptr, col_s, val_s, y_bf, s2, (bf16*)nullptr);

  // --- outputs ---
  k_gather<<<200000, 256, 0, stream>>>(s1, s2, pos_src, pos_dst, neg_src, neg_dst, out);
  k_loss_final<<<1, 64, 0, stream>>>(loss_acc, out);
}

// Round 12
// 1110.751 us; speedup vs baseline: 7.6842x; 1.3243x over previous
//
#include <hip/hip_runtime.h>
#include <hip/hip_bf16.h>

#define NFEAT   128
#define NATTRI  500
#define NNODES  100000
#define NEDGES  3200000
#define HCAP    1000000   // nz list capacity (expected ~500K)

typedef __hip_bfloat16 bf16;
typedef __attribute__((ext_vector_type(8))) short short8v;
typedef __attribute__((ext_vector_type(4))) float f32x4;

__device__ __forceinline__ float sigmoidf_(float x) { return 1.0f / (1.0f + __expf(-x)); }
__device__ __forceinline__ float b2f_(short u) {
  return __uint_as_float(((unsigned)(unsigned short)u) << 16);
}

// ---------------------------------------------------------------------------
// f32 -> bf16 cast, 4 elems/thread.
// ---------------------------------------------------------------------------
__global__ __launch_bounds__(256) void k_cvt_bf(const float* __restrict__ src,
                                                bf16* __restrict__ dst, int n)
{
  int i = (blockIdx.x * 256 + threadIdx.x) * 4;
  if (i >= n) return;
  float4 v = *(const float4*)&src[i];
  __hip_bfloat162 a, b;
  a.x = __float2bfloat16(v.x); a.y = __float2bfloat16(v.y);
  b.x = __float2bfloat16(v.z); b.y = __float2bfloat16(v.w);
  *(__hip_bfloat162*)&dst[i]     = a;
  *(__hip_bfloat162*)&dst[i + 2] = b;
}

// ---------------------------------------------------------------------------
// Small conversions: W0t[128][256], W1t[128][128], attr_bf[500][128].
// ---------------------------------------------------------------------------
__global__ __launch_bounds__(256) void k_cvt_small(
    const float* __restrict__ W0, const float* __restrict__ W1,
    const float* __restrict__ emb_attr,
    bf16* __restrict__ W0t, bf16* __restrict__ W1t, bf16* __restrict__ attrb)
{
  int i = blockIdx.x * 256 + threadIdx.x;
  if (i < 32768) {
    int n = i >> 8, k = i & 255;
    W0t[i] = __float2bfloat16(W0[k * 128 + n]);
  } else if (i < 49152) {
    int j = i - 32768;
    int n = j >> 7, k = j & 127;
    W1t[j] = __float2bfloat16(W1[k * 128 + n]);
  } else if (i < 113152) {
    int j = i - 49152;
    attrb[j] = __float2bfloat16(emb_attr[j]);
  }
}

// ---------------------------------------------------------------------------
// H nonzero extraction
// ---------------------------------------------------------------------------
__global__ __launch_bounds__(256) void k_hnz_count(
    const float* __restrict__ H, int* __restrict__ hcnt)
{
  const int a   = blockIdx.y;
  const int off = blockIdx.x * 1024 + threadIdx.x * 4;
  if (off + 3 < NNODES) {
    float4 h4 = *(const float4*)&H[(size_t)a * NNODES + off];
    if (h4.x > 0.5f) atomicAdd(&hcnt[off + 0], 1);
    if (h4.y > 0.5f) atomicAdd(&hcnt[off + 1], 1);
    if (h4.z > 0.5f) atomicAdd(&hcnt[off + 2], 1);
    if (h4.w > 0.5f) atomicAdd(&hcnt[off + 3], 1);
  } else {
    for (int j = 0; j < 4; ++j) {
      int n = off + j;
      if (n < NNODES && H[(size_t)a * NNODES + n] > 0.5f) atomicAdd(&hcnt[n], 1);
    }
  }
}

__global__ __launch_bounds__(256) void k_hnz_place(
    const float* __restrict__ H, int* __restrict__ hcursor,
    int* __restrict__ hattr, int* __restrict__ hnode)
{
  const int a   = blockIdx.y;
  const int off = blockIdx.x * 1024 + threadIdx.x * 4;
  if (off + 3 < NNODES) {
    float4 h4 = *(const float4*)&H[(size_t)a * NNODES + off];
    float hv[4] = {h4.x, h4.y, h4.z, h4.w};
    #pragma unroll
    for (int j = 0; j < 4; ++j) {
      if (hv[j] > 0.5f) {
        int pos = atomicAdd(&hcursor[off + j], 1);
        if (pos < HCAP) { hattr[pos] = a; hnode[pos] = off + j; }
      }
    }
  } else {
    for (int j = 0; j < 4; ++j) {
      int n = off + j;
      if (n < NNODES && H[(size_t)a * NNODES + n] > 0.5f) {
        int pos = atomicAdd(&hcursor[n], 1);
        if (pos < HCAP) { hattr[pos] = a; hnode[pos] = n; }
      }
    }
  }
}

// ---------------------------------------------------------------------------
// Hacc[n] = sum of emb_attr rows over H-nonzeros -> bf16.
// ---------------------------------------------------------------------------
__global__ __launch_bounds__(256) void k_hacc_sparse(
    const int* __restrict__ hrow_ptr, const int* __restrict__ hattr,
    const float* __restrict__ emb_attr, bf16* __restrict__ Haccb)
{
  int n = blockIdx.x * 4 + (threadIdx.x >> 6);
  if (n >= NNODES) return;
  int lane = threadIdx.x & 63;
  int s = hrow_ptr[n], e = min(hrow_ptr[n + 1], HCAP);
  int f = lane * 2;
  float ax = 0.f, ay = 0.f;
  for (int i = s; i < e; ++i) {
    int a = hattr[i];
    float2 v = *(const float2*)&emb_attr[a * 128 + f];
    ax += v.x; ay += v.y;
  }
  __hip_bfloat162 o;
  o.x = __float2bfloat16(ax); o.y = __float2bfloat16(ay);
  *(__hip_bfloat162*)&Haccb[(size_t)n * 128 + f] = o;
}

// ---------------------------------------------------------------------------
// MFMA GEMM: Y[n][c] = Xcat@W + b, bf16 out. 128x128 tile, 4 waves.
// ---------------------------------------------------------------------------
template<int KTOT>
__global__ __launch_bounds__(256) void k_gemm_mfma(
    const bf16* __restrict__ X0, const bf16* __restrict__ X1,
    const bf16* __restrict__ Wt, const float* __restrict__ bias,
    bf16* __restrict__ Y)
{
  __shared__ __align__(16) short sX[128 * 72];
  __shared__ __align__(16) short sW[128 * 72];
  const int t = threadIdx.x;
  const int w = t >> 6, l = t & 63;
  const int lrow = l & 15, lk = (l >> 4) * 8;
  const int r0 = blockIdx.x * 128;

  f32x4 acc[2][8];
  #pragma unroll
  for (int m2 = 0; m2 < 2; ++m2)
    #pragma unroll
    for (int nf = 0; nf < 8; ++nf)
      acc[m2][nf] = (f32x4){0.f, 0.f, 0.f, 0.f};

  for (int kc = 0; kc < KTOT; kc += 64) {
    __syncthreads();
    {
      int row = t >> 1, ks = (t & 1) * 32;
      int n = r0 + row;
      int gk = kc + ks;
      const bf16* src = X0; int k0 = gk;
      if (KTOT == 256 && gk >= 128) { src = X1; k0 = gk - 128; }
      short* d = &sX[row * 72 + ks];
      if (n < NNODES) {
        const short* p = (const short*)&src[(size_t)n * 128 + k0];
        #pragma unroll
        for (int i = 0; i < 4; ++i) *(short8v*)&d[i * 8] = *(const short8v*)&p[i * 8];
      } else {
        short8v z = (short8v){0,0,0,0,0,0,0,0};
        #pragma unroll
        for (int i = 0; i < 4; ++i) *(short8v*)&d[i * 8] = z;
      }
    }
    {
      int nrow = t >> 1, ks = (t & 1) * 32;
      const short* p = (const short*)&Wt[(size_t)nrow * KTOT + kc + ks];
      short* d = &sW[nrow * 72 + ks];
      #pragma unroll
      for (int i = 0; i < 4; ++i) *(short8v*)&d[i * 8] = *(const short8v*)&p[i * 8];
    }
    __syncthreads();
    #pragma unroll
    for (int kf = 0; kf < 2; ++kf) {
      short8v a0 = *(const short8v*)&sX[(w * 32 +      lrow) * 72 + kf * 32 + lk];
      short8v a1 = *(const short8v*)&sX[(w * 32 + 16 + lrow) * 72 + kf * 32 + lk];
      #pragma unroll
      for (int nf = 0; nf < 8; ++nf) {
        short8v b = *(const short8v*)&sW[(nf * 16 + lrow) * 72 + kf * 32 + lk];
        acc[0][nf] = __builtin_amdgcn_mfma_f32_16x16x32_bf16(a0, b, acc[0][nf], 0, 0, 0);
        acc[1][nf] = __builtin_amdgcn_mfma_f32_16x16x32_bf16(a1, b, acc[1][nf], 0, 0, 0);
      }
    }
  }
  #pragma unroll
  for (int m2 = 0; m2 < 2; ++m2) {
    int rbase = r0 + w * 32 + m2 * 16 + (l >> 4) * 4;
    #pragma unroll
    for (int nf = 0; nf < 8; ++nf) {
      int col = nf * 16 + lrow;
      float bv = bias[col];
      #pragma unroll
      for (int ri = 0; ri < 4; ++ri) {
        int grow = rbase + ri;
        if (grow < NNODES)
          Y[(size_t)grow * 128 + col] = __float2bfloat16(acc[m2][nf][ri] + bv);
      }
    }
  }
}

// ---------------------------------------------------------------------------
// MFMA loss base: sum 0.1*sigmoid(emb_node @ emb_attr^T)^2 over all pairs.
// ---------------------------------------------------------------------------
__global__ __launch_bounds__(256) void k_loss_mfma(
    const bf16* __restrict__ Xb, const bf16* __restrict__ Ab,
    float* __restrict__ loss_acc)
{
  __shared__ __align__(16) short sX[128 * 72];
  __shared__ __align__(16) short sW[128 * 72];
  __shared__ float red[4];
  const int t = threadIdx.x;
  const int w = t >> 6, l = t & 63;
  const int lrow = l & 15, lk = (l >> 4) * 8;
  const int r0 = blockIdx.x * 128;
  const int a0 = blockIdx.y * 128;

  f32x4 acc[2][8];
  #pragma unroll
  for (int m2 = 0; m2 < 2; ++m2)
    #pragma unroll
    for (int nf = 0; nf < 8; ++nf)
      acc[m2][nf] = (f32x4){0.f, 0.f, 0.f, 0.f};

  for (int kc = 0; kc < 128; kc += 64) {
    __syncthreads();
    {
      int row = t >> 1, ks = (t & 1) * 32;
      int n = r0 + row;
      short* d = &sX[row * 72 + ks];
      if (n < NNODES) {
        const short* p = (const short*)&Xb[(size_t)n * 128 + kc + ks];
        #pragma unroll
        for (int i = 0; i < 4; ++i) *(short8v*)&d[i * 8] = *(const short8v*)&p[i * 8];
      } else {
        short8v z = (short8v){0,0,0,0,0,0,0,0};
        #pragma unroll
        for (int i = 0; i < 4; ++i) *(short8v*)&d[i * 8] = z;
      }
    }
    {
      int nrow = t >> 1, ks = (t & 1) * 32;
      int a = a0 + nrow;
      short* d = &sW[nrow * 72 + ks];
      if (a < NATTRI) {
        const short* p = (const short*)&Ab[(size_t)a * 128 + kc + ks];
        #pragma unroll
        for (int i = 0; i < 4; ++i) *(short8v*)&d[i * 8] = *(const short8v*)&p[i * 8];
      } else {
        short8v z = (short8v){0,0,0,0,0,0,0,0};
        #pragma unroll
        for (int i = 0; i < 4; ++i) *(short8v*)&d[i * 8] = z;
      }
    }
    __syncthreads();
    #pragma unroll
    for (int kf = 0; kf < 2; ++kf) {
      short8v av0 = *(const short8v*)&sX[(w * 32 +      lrow) * 72 + kf * 32 + lk];
      short8v av1 = *(const short8v*)&sX[(w * 32 + 16 + lrow) * 72 + kf * 32 + lk];
      #pragma unroll
      for (int nf = 0; nf < 8; ++nf) {
        short8v b = *(const short8v*)&sW[(nf * 16 + lrow) * 72 + kf * 32 + lk];
        acc[0][nf] = __builtin_amdgcn_mfma_f32_16x16x32_bf16(av0, b, acc[0][nf], 0, 0, 0);
        acc[1][nf] = __builtin_amdgcn_mfma_f32_16x16x32_bf16(av1, b, acc[1][nf], 0, 0, 0);
      }
    }
  }
  float lacc = 0.f;
  #pragma unroll
  for (int m2 = 0; m2 < 2; ++m2) {
    int rbase = r0 + w * 32 + m2 * 16 + (l >> 4) * 4;
    #pragma unroll
    for (int nf = 0; nf < 8; ++nf) {
      int col = a0 + nf * 16 + lrow;
      if (col < NATTRI) {
        #pragma unroll
        for (int ri = 0; ri < 4; ++ri) {
          int grow = rbase + ri;
          if (grow < NNODES) {
            float s = sigmoidf_(acc[m2][nf][ri]);
            lacc += 0.1f * s * s;
          }
        }
      }
    }
  }
  for (int off = 32; off; off >>= 1) lacc += __shfl_xor(lacc, off, 64);
  if (l == 0) red[w] = lacc;
  __syncthreads();
  if (t == 0) atomicAdd(loss_acc, red[0] + red[1] + red[2] + red[3]);
}

// ---------------------------------------------------------------------------
// Flat loss correction: wave per nz entry, grid-stride.
// ---------------------------------------------------------------------------
__global__ __launch_bounds__(256) void k_loss_corr_flat(
    const int* __restrict__ hnode, const int* __restrict__ hattr,
    const int* __restrict__ hrow_ptr,
    const float* __restrict__ emb_attr, const float* __restrict__ emb_node,
    float* __restrict__ loss_acc)
{
  __shared__ float red[4];
  const int total = min(hrow_ptr[NNODES], HCAP);
  const int lane = threadIdx.x & 63;
  const int wv = (blockIdx.x * 256 + threadIdx.x) >> 6;
  const int nw = gridDim.x * 4;
  float part = 0.f;
  for (int i = wv; i < total; i += nw) {
    int n = hnode[i];
    int a = hattr[i];
    float2 x = *(const float2*)&emb_node[(size_t)n * 128 + lane * 2];
    float2 w = *(const float2*)&emb_attr[a * 128 + lane * 2];
    float d = x.x * w.x + x.y * w.y;
    for (int off = 32; off; off >>= 1) d += __shfl_xor(d, off, 64);
    if (lane == 0) {
      float sg = sigmoidf_(d);
      float om = 1.f - sg;
      part += 2.0f * om * om - 0.1f * sg * sg;
    }
  }
  if (lane == 0) red[threadIdx.x >> 6] = part;
  __syncthreads();
  if (threadIdx.x == 0) atomicAdd(loss_acc, red[0] + red[1] + red[2] + red[3]);
}

// ---------------------------------------------------------------------------
// Edge CSR build: hist + 3-phase parallel scan + scatter
// ---------------------------------------------------------------------------
__global__ __launch_bounds__(256) void k_hist(const int* __restrict__ g_row,
                                              int* __restrict__ deg) {
  int e = blockIdx.x * 256 + threadIdx.x;
  if (e < NEDGES) atomicAdd(&deg[g_row[e]], 1);
}

__global__ __launch_bounds__(256) void k_scan_p1(const int* __restrict__ deg,
                                                 int* __restrict__ bsum)
{
  __shared__ int wsum[4];
  int base = blockIdx.x * 1024 + threadIdx.x * 4;
  int s = 0;
  #pragma unroll
  for (int j = 0; j < 4; ++j) { int i = base + j; if (i < NNODES) s += deg[i]; }
  for (int off = 32; off; off >>= 1) s += __shfl_down(s, off, 64);
  if ((threadIdx.x & 63) == 0) wsum[threadIdx.x >> 6] = s;
  __syncthreads();
  if (threadIdx.x == 0) bsum[blockIdx.x] = wsum[0] + wsum[1] + wsum[2] + wsum[3];
}

__global__ void k_scan_p2(const int* __restrict__ bsum, int* __restrict__ boff,
                          int* __restrict__ row_ptr, int nb)
{
  __shared__ int tmp[128];
  int t = threadIdx.x;
  tmp[t] = (t < nb) ? bsum[t] : 0;
  __syncthreads();
  if (t == 0) {
    int r = 0;
    for (int i = 0; i < nb; ++i) { int v = tmp[i]; boff[i] = r; r += v; }
    row_ptr[NNODES] = r;
  }
}

__global__ __launch_bounds__(256) void k_scan_p3(
    const int* __restrict__ deg, const int* __restrict__ boff,
    int* __restrict__ row_ptr, int* __restrict__ cursor)
{
  __shared__ int tsum[256];
  const int t = threadIdx.x;
  int base = blockIdx.x * 1024 + t * 4;
  int v[4]; int s = 0;
  #pragma unroll
  for (int j = 0; j < 4; ++j) { int i = base + j; v[j] = (i < NNODES) ? deg[i] : 0; s += v[j]; }
  tsum[t] = s;
  __syncthreads();
  for (int off = 1; off < 256; off <<= 1) {
    int y = (t >= off) ? tsum[t - off] : 0;
    __syncthreads();
    tsum[t] += y;
    __syncthreads();
  }
  int run = boff[blockIdx.x] + tsum[t] - s;
  #pragma unroll
  for (int j = 0; j < 4; ++j) {
    int i = base + j;
    if (i < NNODES) { row_ptr[i] = run; cursor[i] = run; run += v[j]; }
  }
}

__global__ __launch_bounds__(256) void k_scatter(
    const int* __restrict__ g_row, const int* __restrict__ g_col,
    const float* __restrict__ g_val, int* __restrict__ cursor,
    int* __restrict__ col_s, float* __restrict__ val_s) {
  int e = blockIdx.x * 256 + threadIdx.x;
  if (e < NEDGES) {
    int r = g_row[e];
    int p = atomicAdd(&cursor[r], 1);
    col_s[p] = g_col[e];
    val_s[p] = g_val[e];
  }
}

// ---------------------------------------------------------------------------
// SpMM v2: wave per row, 4 edges/iter, 16B bf16x8 per lane.
// lane: eg = lane>>4 (edge subgroup), fg = (lane&15)*8 (feature octet).
// Butterfly (16,32) sums edge subgroups; lanes 0-15 store.
// ---------------------------------------------------------------------------
template<bool WRITE_BF>
__global__ __launch_bounds__(256) void k_spmm(
    const int* __restrict__ row_ptr, const int* __restrict__ col_s,
    const float* __restrict__ val_s, const bf16* __restrict__ X,
    float* __restrict__ Y, bf16* __restrict__ Yb)
{
  int w = (int)((blockIdx.x * 256u + threadIdx.x) >> 6);
  if (w >= NNODES) return;
  const int lane = threadIdx.x & 63;
  const int eg = lane >> 4;
  const int fg = (lane & 15) * 8;
  const int s = row_ptr[w], e = row_ptr[w + 1];

  float acc[8] = {0.f, 0.f, 0.f, 0.f, 0.f, 0.f, 0.f, 0.f};
  for (int i = s; i < e; i += 4) {
    int ii = i + eg;
    bool ok = ii < e;
    int c = ok ? col_s[ii] : 0;
    float v = ok ? val_s[ii] : 0.f;
    if (ok) {
      short8v xv = *(const short8v*)&X[(size_t)c * 128 + fg];
      #pragma unroll
      for (int j = 0; j < 8; ++j)
        acc[j] = fmaf(v, b2f_(xv[j]), acc[j]);
    }
  }
  #pragma unroll
  for (int j = 0; j < 8; ++j) {
    acc[j] += __shfl_xor(acc[j], 16, 64);
    acc[j] += __shfl_xor(acc[j], 32, 64);
  }
  if (lane < 16) {
    float4 o0 = make_float4(acc[0], acc[1], acc[2], acc[3]);
    float4 o1 = make_float4(acc[4], acc[5], acc[6], acc[7]);
    *(float4*)&Y[(size_t)w * 128 + fg]     = o0;
    *(float4*)&Y[(size_t)w * 128 + fg + 4] = o1;
    if (WRITE_BF) {
      short8v ob;
      #pragma unroll
      for (int j = 0; j < 8; ++j) {
        __hip_bfloat16 h = __float2bfloat16(acc[j]);
        ob[j] = *(short*)&h;
      }
      *(short8v*)&Yb[(size_t)w * 128 + fg] = ob;
    }
  }
}

// ---------------------------------------------------------------------------
// Gather v2: 2 output rows per wave, float4 (16B) per lane, fused l2norm.
// ---------------------------------------------------------------------------
__global__ __launch_bounds__(256) void k_gather(
    const float* __restrict__ s1, const float* __restrict__ s2,
    const int* __restrict__ i0, const int* __restrict__ i1,
    const int* __restrict__ i2, const int* __restrict__ i3,
    float* __restrict__ out)
{
  long wid = ((long)blockIdx.x * 256 + threadIdx.x) >> 6;   // 0..399999
  int lane = threadIdx.x & 63;
  long gw = wid * 2 + (lane >> 5);                          // 0..799999
  int fl = (lane & 31) * 4;
  int o   = (int)(gw / 200000);
  int rem = (int)(gw % 200000);
  int l = rem / 100000;
  int i = rem % 100000;
  const int* idx = (o == 0) ? i0 : (o == 1) ? i1 : (o == 2) ? i2 : i3;
  int node = idx[i];
  const float* src = (l == 0) ? s1 : s2;
  float4 v = *(const float4*)&src[(size_t)node * 128 + fl];
  float ss = v.x * v.x + v.y * v.y + v.z * v.z + v.w * v.w;
  #pragma unroll
  for (int off = 1; off < 32; off <<= 1) ss += __shfl_xor(ss, off, 64);
  float inv = 1.0f / fmaxf(sqrtf(ss), 1e-12f);
  float4 ov = make_float4(v.x * inv, v.y * inv, v.z * inv, v.w * inv);
  *(float4*)&out[gw * 128 + fl] = ov;
}

__global__ void k_loss_final(const float* __restrict__ loss_acc, float* __restrict__ out) {
  if (threadIdx.x == 0)
    out[102400000] = loss_acc[0] * (1.0f / 50000000.0f);
}

// ---------------------------------------------------------------------------
extern "C" void kernel_launch(void* const* d_in, const int* in_sizes, int n_in,
                              void* d_out, int out_size, void* d_ws, size_t ws_size,
                              hipStream_t stream)
{
  const float* emb_attr = (const float*)d_in[0];
  const float* emb_node = (const float*)d_in[1];
  const float* W0 = (const float*)d_in[2];
  const float* b0 = (const float*)d_in[3];
  const float* W1 = (const float*)d_in[4];
  const float* b1 = (const float*)d_in[5];
  const float* H  = (const float*)d_in[6];
  const float* g_val = (const float*)d_in[7];
  const int* g_row = (const int*)d_in[8];
  const int* g_col = (const int*)d_in[9];
  const int* pos_src = (const int*)d_in[10];
  const int* pos_dst = (const int*)d_in[11];
  const int* neg_src = (const int*)d_in[12];
  const int* neg_dst = (const int*)d_in[13];
  float* out = (float*)d_out;

  const size_t NF = 12800000;
  const int NB = (NNODES + 1023) / 1024;               // 98 scan blocks

  char* base = (char*)d_out;
  bf16*  embn_bf = (bf16*)base;                        // 25.6 MB
  bf16*  Hacc_bf = embn_bf + NF;                       // 25.6 MB
  bf16*  y_bf    = Hacc_bf + NF;                       // 25.6 MB
  bf16*  s1_bf   = y_bf + NF;                          // 25.6 MB
  bf16*  W0t_bf  = s1_bf + NF;                         // 64 KB
  bf16*  W1t_bf  = W0t_bf + 32768;                     // 32 KB
  bf16*  attr_bf = W1t_bf + 16384;                     // 125 KB
  int*   row_ptr  = (int*)(attr_bf + 64000);
  int*   deg      = row_ptr + 100004;
  int*   cursor   = deg + 100000;
  int*   hrow_ptr = cursor + 100000;
  int*   hcnt     = hrow_ptr + 100004;
  int*   hcursor  = hcnt + 100000;
  int*   bsum     = hcursor + 100000;                  // 128
  int*   boff     = bsum + 128;                        // 128
  int*   col_s    = boff + 128;                        // 3.2M
  int*   hattr    = col_s + 3200000;                   // 1M
  int*   hnode    = hattr + HCAP;                      // 1M
  float* val_s    = (float*)(hnode + HCAP);            // 3.2M

  float* s1 = (float*)d_ws;                            // 51.2 MB
  float* s2 = s1 + NF;                                 // 51.2 MB
  float* loss_acc = s2 + NF;

  hipMemsetAsync(loss_acc, 0, 16, stream);
  hipMemsetAsync(deg, 0, NNODES * sizeof(int), stream);
  hipMemsetAsync(hcnt, 0, NNODES * sizeof(int), stream);

  // --- bf16 conversions ---
  k_cvt_bf<<<12500, 256, 0, stream>>>(emb_node, embn_bf, (int)NF);
  k_cvt_small<<<442, 256, 0, stream>>>(W0, W1, emb_attr, W0t_bf, W1t_bf, attr_bf);

  // --- sparse H extraction ---
  dim3 hgrid(NB, NATTRI);
  k_hnz_count<<<hgrid, 256, 0, stream>>>(H, hcnt);
  k_scan_p1<<<NB, 256, 0, stream>>>(hcnt, bsum);
  k_scan_p2<<<1, 128, 0, stream>>>(bsum, boff, hrow_ptr, NB);
  k_scan_p3<<<NB, 256, 0, stream>>>(hcnt, boff, hrow_ptr, hcursor);
  k_hnz_place<<<hgrid, 256, 0, stream>>>(H, hcursor, hattr, hnode);
  k_hacc_sparse<<<NNODES / 4, 256, 0, stream>>>(hrow_ptr, hattr, emb_attr, Hacc_bf);

  // --- loss: MFMA base + flat sparse correction ---
  dim3 lgrid((NNODES + 127) / 128, 4);
  k_loss_mfma<<<lgrid, 256, 0, stream>>>(embn_bf, attr_bf, loss_acc);
  k_loss_corr_flat<<<4096, 256, 0, stream>>>(hnode, hattr, hrow_ptr, emb_attr, emb_node, loss_acc);

  // --- edge CSR ---
  k_hist<<<(NEDGES + 255) / 256, 256, 0, stream>>>(g_row, deg);
  k_scan_p1<<<NB, 256, 0, stream>>>(deg, bsum);
  k_scan_p2<<<1, 128, 0, stream>>>(bsum, boff, row_ptr, NB);
  k_scan_p3<<<NB, 256, 0, stream>>>(deg, boff, row_ptr, cursor);
  k_scatter<<<(NEDGES + 255) / 256, 256, 0, stream>>>(g_row, g_col, g_val, cursor, col_s, val_s);

  // --- GNN layers ---
  const int ggrid = (NNODES + 127) / 128;   // 782
  k_gemm_mfma<256><<<ggrid, 256, 0, stream>>>(embn_bf, Hacc_bf, W0t_bf, b0, y_bf);
  k_spmm<true><<<(NNODES * 64) / 256, 256, 0, stream>>>(row_ptr, col_s, val_s, y_bf, s1, s1_bf);
  k_gemm_mfma<128><<<ggrid, 256, 0, stream>>>(s1_bf, (const bf16*)nullptr, W1t_bf, b1, y_bf);
  k_spmm<false><<<(NNODES * 64) / 256, 256, 0, stream>>>(row_ptr, col_s, val_s, y_bf, s2, (bf16*)nullptr);

  // --- outputs ---
  k_gather<<<100000, 256, 0, stream>>>(s1, s2, pos_src, pos_dst, neg_src, neg_dst, out);
  k_loss_final<<<1, 64, 0, stream>>>(loss_acc, out);
}

// Round 13
// 1091.929 us; speedup vs baseline: 7.8166x; 1.0172x over previous
//
#include <hip/hip_runtime.h>
#include <hip/hip_bf16.h>

#define NFEAT   128
#define NATTRI  500
#define NNODES  100000
#define NEDGES  3200000
#define HCAP    1000000   // nz list capacity (expected ~500K)

typedef __hip_bfloat16 bf16;
typedef __attribute__((ext_vector_type(8))) short short8v;
typedef __attribute__((ext_vector_type(4))) float f32x4;

__device__ __forceinline__ float sigmoidf_(float x) { return 1.0f / (1.0f + __expf(-x)); }
__device__ __forceinline__ float b2f_(short u) {
  return __uint_as_float(((unsigned)(unsigned short)u) << 16);
}

// ---------------------------------------------------------------------------
// f32 -> bf16 cast, 4 elems/thread.
// ---------------------------------------------------------------------------
__global__ __launch_bounds__(256) void k_cvt_bf(const float* __restrict__ src,
                                                bf16* __restrict__ dst, int n)
{
  int i = (blockIdx.x * 256 + threadIdx.x) * 4;
  if (i >= n) return;
  float4 v = *(const float4*)&src[i];
  __hip_bfloat162 a, b;
  a.x = __float2bfloat16(v.x); a.y = __float2bfloat16(v.y);
  b.x = __float2bfloat16(v.z); b.y = __float2bfloat16(v.w);
  *(__hip_bfloat162*)&dst[i]     = a;
  *(__hip_bfloat162*)&dst[i + 2] = b;
}

// ---------------------------------------------------------------------------
// Small conversions: W0t[128][256], W1t[128][128], attr_bf[500][128].
// ---------------------------------------------------------------------------
__global__ __launch_bounds__(256) void k_cvt_small(
    const float* __restrict__ W0, const float* __restrict__ W1,
    const float* __restrict__ emb_attr,
    bf16* __restrict__ W0t, bf16* __restrict__ W1t, bf16* __restrict__ attrb)
{
  int i = blockIdx.x * 256 + threadIdx.x;
  if (i < 32768) {
    int n = i >> 8, k = i & 255;
    W0t[i] = __float2bfloat16(W0[k * 128 + n]);
  } else if (i < 49152) {
    int j = i - 32768;
    int n = j >> 7, k = j & 127;
    W1t[j] = __float2bfloat16(W1[k * 128 + n]);
  } else if (i < 113152) {
    int j = i - 49152;
    attrb[j] = __float2bfloat16(emb_attr[j]);
  }
}

// ---------------------------------------------------------------------------
// H nonzero extraction
// ---------------------------------------------------------------------------
__global__ __launch_bounds__(256) void k_hnz_count(
    const float* __restrict__ H, int* __restrict__ hcnt)
{
  const int a   = blockIdx.y;
  const int off = blockIdx.x * 1024 + threadIdx.x * 4;
  if (off + 3 < NNODES) {
    float4 h4 = *(const float4*)&H[(size_t)a * NNODES + off];
    if (h4.x > 0.5f) atomicAdd(&hcnt[off + 0], 1);
    if (h4.y > 0.5f) atomicAdd(&hcnt[off + 1], 1);
    if (h4.z > 0.5f) atomicAdd(&hcnt[off + 2], 1);
    if (h4.w > 0.5f) atomicAdd(&hcnt[off + 3], 1);
  } else {
    for (int j = 0; j < 4; ++j) {
      int n = off + j;
      if (n < NNODES && H[(size_t)a * NNODES + n] > 0.5f) atomicAdd(&hcnt[n], 1);
    }
  }
}

__global__ __launch_bounds__(256) void k_hnz_place(
    const float* __restrict__ H, int* __restrict__ hcursor,
    int* __restrict__ hattr, int* __restrict__ hnode)
{
  const int a   = blockIdx.y;
  const int off = blockIdx.x * 1024 + threadIdx.x * 4;
  if (off + 3 < NNODES) {
    float4 h4 = *(const float4*)&H[(size_t)a * NNODES + off];
    float hv[4] = {h4.x, h4.y, h4.z, h4.w};
    #pragma unroll
    for (int j = 0; j < 4; ++j) {
      if (hv[j] > 0.5f) {
        int pos = atomicAdd(&hcursor[off + j], 1);
        if (pos < HCAP) { hattr[pos] = a; hnode[pos] = off + j; }
      }
    }
  } else {
    for (int j = 0; j < 4; ++j) {
      int n = off + j;
      if (n < NNODES && H[(size_t)a * NNODES + n] > 0.5f) {
        int pos = atomicAdd(&hcursor[n], 1);
        if (pos < HCAP) { hattr[pos] = a; hnode[pos] = n; }
      }
    }
  }
}

// ---------------------------------------------------------------------------
// Hacc[n] = sum of emb_attr rows over H-nonzeros -> bf16.
// ---------------------------------------------------------------------------
__global__ __launch_bounds__(256) void k_hacc_sparse(
    const int* __restrict__ hrow_ptr, const int* __restrict__ hattr,
    const float* __restrict__ emb_attr, bf16* __restrict__ Haccb)
{
  int n = blockIdx.x * 4 + (threadIdx.x >> 6);
  if (n >= NNODES) return;
  int lane = threadIdx.x & 63;
  int s = hrow_ptr[n], e = min(hrow_ptr[n + 1], HCAP);
  int f = lane * 2;
  float ax = 0.f, ay = 0.f;
  for (int i = s; i < e; ++i) {
    int a = hattr[i];
    float2 v = *(const float2*)&emb_attr[a * 128 + f];
    ax += v.x; ay += v.y;
  }
  __hip_bfloat162 o;
  o.x = __float2bfloat16(ax); o.y = __float2bfloat16(ay);
  *(__hip_bfloat162*)&Haccb[(size_t)n * 128 + f] = o;
}

// ---------------------------------------------------------------------------
// MFMA GEMM: Y[n][c] = Xcat@W + b, bf16 out. 128x128 tile, 4 waves.
// ---------------------------------------------------------------------------
template<int KTOT>
__global__ __launch_bounds__(256) void k_gemm_mfma(
    const bf16* __restrict__ X0, const bf16* __restrict__ X1,
    const bf16* __restrict__ Wt, const float* __restrict__ bias,
    bf16* __restrict__ Y)
{
  __shared__ __align__(16) short sX[128 * 72];
  __shared__ __align__(16) short sW[128 * 72];
  const int t = threadIdx.x;
  const int w = t >> 6, l = t & 63;
  const int lrow = l & 15, lk = (l >> 4) * 8;
  const int r0 = blockIdx.x * 128;

  f32x4 acc[2][8];
  #pragma unroll
  for (int m2 = 0; m2 < 2; ++m2)
    #pragma unroll
    for (int nf = 0; nf < 8; ++nf)
      acc[m2][nf] = (f32x4){0.f, 0.f, 0.f, 0.f};

  for (int kc = 0; kc < KTOT; kc += 64) {
    __syncthreads();
    {
      int row = t >> 1, ks = (t & 1) * 32;
      int n = r0 + row;
      int gk = kc + ks;
      const bf16* src = X0; int k0 = gk;
      if (KTOT == 256 && gk >= 128) { src = X1; k0 = gk - 128; }
      short* d = &sX[row * 72 + ks];
      if (n < NNODES) {
        const short* p = (const short*)&src[(size_t)n * 128 + k0];
        #pragma unroll
        for (int i = 0; i < 4; ++i) *(short8v*)&d[i * 8] = *(const short8v*)&p[i * 8];
      } else {
        short8v z = (short8v){0,0,0,0,0,0,0,0};
        #pragma unroll
        for (int i = 0; i < 4; ++i) *(short8v*)&d[i * 8] = z;
      }
    }
    {
      int nrow = t >> 1, ks = (t & 1) * 32;
      const short* p = (const short*)&Wt[(size_t)nrow * KTOT + kc + ks];
      short* d = &sW[nrow * 72 + ks];
      #pragma unroll
      for (int i = 0; i < 4; ++i) *(short8v*)&d[i * 8] = *(const short8v*)&p[i * 8];
    }
    __syncthreads();
    #pragma unroll
    for (int kf = 0; kf < 2; ++kf) {
      short8v a0 = *(const short8v*)&sX[(w * 32 +      lrow) * 72 + kf * 32 + lk];
      short8v a1 = *(const short8v*)&sX[(w * 32 + 16 + lrow) * 72 + kf * 32 + lk];
      #pragma unroll
      for (int nf = 0; nf < 8; ++nf) {
        short8v b = *(const short8v*)&sW[(nf * 16 + lrow) * 72 + kf * 32 + lk];
        acc[0][nf] = __builtin_amdgcn_mfma_f32_16x16x32_bf16(a0, b, acc[0][nf], 0, 0, 0);
        acc[1][nf] = __builtin_amdgcn_mfma_f32_16x16x32_bf16(a1, b, acc[1][nf], 0, 0, 0);
      }
    }
  }
  #pragma unroll
  for (int m2 = 0; m2 < 2; ++m2) {
    int rbase = r0 + w * 32 + m2 * 16 + (l >> 4) * 4;
    #pragma unroll
    for (int nf = 0; nf < 8; ++nf) {
      int col = nf * 16 + lrow;
      float bv = bias[col];
      #pragma unroll
      for (int ri = 0; ri < 4; ++ri) {
        int grow = rbase + ri;
        if (grow < NNODES)
          Y[(size_t)grow * 128 + col] = __float2bfloat16(acc[m2][nf][ri] + bv);
      }
    }
  }
}

// ---------------------------------------------------------------------------
// MFMA loss base: sum 0.1*sigmoid(emb_node @ emb_attr^T)^2 over all pairs.
// ---------------------------------------------------------------------------
__global__ __launch_bounds__(256) void k_loss_mfma(
    const bf16* __restrict__ Xb, const bf16* __restrict__ Ab,
    float* __restrict__ loss_acc)
{
  __shared__ __align__(16) short sX[128 * 72];
  __shared__ __align__(16) short sW[128 * 72];
  __shared__ float red[4];
  const int t = threadIdx.x;
  const int w = t >> 6, l = t & 63;
  const int lrow = l & 15, lk = (l >> 4) * 8;
  const int r0 = blockIdx.x * 128;
  const int a0 = blockIdx.y * 128;

  f32x4 acc[2][8];
  #pragma unroll
  for (int m2 = 0; m2 < 2; ++m2)
    #pragma unroll
    for (int nf = 0; nf < 8; ++nf)
      acc[m2][nf] = (f32x4){0.f, 0.f, 0.f, 0.f};

  for (int kc = 0; kc < 128; kc += 64) {
    __syncthreads();
    {
      int row = t >> 1, ks = (t & 1) * 32;
      int n = r0 + row;
      short* d = &sX[row * 72 + ks];
      if (n < NNODES) {
        const short* p = (const short*)&Xb[(size_t)n * 128 + kc + ks];
        #pragma unroll
        for (int i = 0; i < 4; ++i) *(short8v*)&d[i * 8] = *(const short8v*)&p[i * 8];
      } else {
        short8v z = (short8v){0,0,0,0,0,0,0,0};
        #pragma unroll
        for (int i = 0; i < 4; ++i) *(short8v*)&d[i * 8] = z;
      }
    }
    {
      int nrow = t >> 1, ks = (t & 1) * 32;
      int a = a0 + nrow;
      short* d = &sW[nrow * 72 + ks];
      if (a < NATTRI) {
        const short* p = (const short*)&Ab[(size_t)a * 128 + kc + ks];
        #pragma unroll
        for (int i = 0; i < 4; ++i) *(short8v*)&d[i * 8] = *(const short8v*)&p[i * 8];
      } else {
        short8v z = (short8v){0,0,0,0,0,0,0,0};
        #pragma unroll
        for (int i = 0; i < 4; ++i) *(short8v*)&d[i * 8] = z;
      }
    }
    __syncthreads();
    #pragma unroll
    for (int kf = 0; kf < 2; ++kf) {
      short8v av0 = *(const short8v*)&sX[(w * 32 +      lrow) * 72 + kf * 32 + lk];
      short8v av1 = *(const short8v*)&sX[(w * 32 + 16 + lrow) * 72 + kf * 32 + lk];
      #pragma unroll
      for (int nf = 0; nf < 8; ++nf) {
        short8v b = *(const short8v*)&sW[(nf * 16 + lrow) * 72 + kf * 32 + lk];
        acc[0][nf] = __builtin_amdgcn_mfma_f32_16x16x32_bf16(av0, b, acc[0][nf], 0, 0, 0);
        acc[1][nf] = __builtin_amdgcn_mfma_f32_16x16x32_bf16(av1, b, acc[1][nf], 0, 0, 0);
      }
    }
  }
  float lacc = 0.f;
  #pragma unroll
  for (int m2 = 0; m2 < 2; ++m2) {
    int rbase = r0 + w * 32 + m2 * 16 + (l >> 4) * 4;
    #pragma unroll
    for (int nf = 0; nf < 8; ++nf) {
      int col = a0 + nf * 16 + lrow;
      if (col < NATTRI) {
        #pragma unroll
        for (int ri = 0; ri < 4; ++ri) {
          int grow = rbase + ri;
          if (grow < NNODES) {
            float s = sigmoidf_(acc[m2][nf][ri]);
            lacc += 0.1f * s * s;
          }
        }
      }
    }
  }
  for (int off = 32; off; off >>= 1) lacc += __shfl_xor(lacc, off, 64);
  if (l == 0) red[w] = lacc;
  __syncthreads();
  if (t == 0) atomicAdd(loss_acc, red[0] + red[1] + red[2] + red[3]);
}

// ---------------------------------------------------------------------------
// Flat loss correction: wave per nz entry, grid-stride.
// ---------------------------------------------------------------------------
__global__ __launch_bounds__(256) void k_loss_corr_flat(
    const int* __restrict__ hnode, const int* __restrict__ hattr,
    const int* __restrict__ hrow_ptr,
    const float* __restrict__ emb_attr, const float* __restrict__ emb_node,
    float* __restrict__ loss_acc)
{
  __shared__ float red[4];
  const int total = min(hrow_ptr[NNODES], HCAP);
  const int lane = threadIdx.x & 63;
  const int wv = (blockIdx.x * 256 + threadIdx.x) >> 6;
  const int nw = gridDim.x * 4;
  float part = 0.f;
  for (int i = wv; i < total; i += nw) {
    int n = hnode[i];
    int a = hattr[i];
    float2 x = *(const float2*)&emb_node[(size_t)n * 128 + lane * 2];
    float2 w = *(const float2*)&emb_attr[a * 128 + lane * 2];
    float d = x.x * w.x + x.y * w.y;
    for (int off = 32; off; off >>= 1) d += __shfl_xor(d, off, 64);
    if (lane == 0) {
      float sg = sigmoidf_(d);
      float om = 1.f - sg;
      part += 2.0f * om * om - 0.1f * sg * sg;
    }
  }
  if (lane == 0) red[threadIdx.x >> 6] = part;
  __syncthreads();
  if (threadIdx.x == 0) atomicAdd(loss_acc, red[0] + red[1] + red[2] + red[3]);
}

// ---------------------------------------------------------------------------
// Edge CSR build: hist + 3-phase parallel scan + scatter
// ---------------------------------------------------------------------------
__global__ __launch_bounds__(256) void k_hist(const int* __restrict__ g_row,
                                              int* __restrict__ deg) {
  int e = blockIdx.x * 256 + threadIdx.x;
  if (e < NEDGES) atomicAdd(&deg[g_row[e]], 1);
}

__global__ __launch_bounds__(256) void k_scan_p1(const int* __restrict__ deg,
                                                 int* __restrict__ bsum)
{
  __shared__ int wsum[4];
  int base = blockIdx.x * 1024 + threadIdx.x * 4;
  int s = 0;
  #pragma unroll
  for (int j = 0; j < 4; ++j) { int i = base + j; if (i < NNODES) s += deg[i]; }
  for (int off = 32; off; off >>= 1) s += __shfl_down(s, off, 64);
  if ((threadIdx.x & 63) == 0) wsum[threadIdx.x >> 6] = s;
  __syncthreads();
  if (threadIdx.x == 0) bsum[blockIdx.x] = wsum[0] + wsum[1] + wsum[2] + wsum[3];
}

__global__ void k_scan_p2(const int* __restrict__ bsum, int* __restrict__ boff,
                          int* __restrict__ row_ptr, int nb)
{
  __shared__ int tmp[128];
  int t = threadIdx.x;
  tmp[t] = (t < nb) ? bsum[t] : 0;
  __syncthreads();
  if (t == 0) {
    int r = 0;
    for (int i = 0; i < nb; ++i) { int v = tmp[i]; boff[i] = r; r += v; }
    row_ptr[NNODES] = r;
  }
}

__global__ __launch_bounds__(256) void k_scan_p3(
    const int* __restrict__ deg, const int* __restrict__ boff,
    int* __restrict__ row_ptr, int* __restrict__ cursor)
{
  __shared__ int tsum[256];
  const int t = threadIdx.x;
  int base = blockIdx.x * 1024 + t * 4;
  int v[4]; int s = 0;
  #pragma unroll
  for (int j = 0; j < 4; ++j) { int i = base + j; v[j] = (i < NNODES) ? deg[i] : 0; s += v[j]; }
  tsum[t] = s;
  __syncthreads();
  for (int off = 1; off < 256; off <<= 1) {
    int y = (t >= off) ? tsum[t - off] : 0;
    __syncthreads();
    tsum[t] += y;
    __syncthreads();
  }
  int run = boff[blockIdx.x] + tsum[t] - s;
  #pragma unroll
  for (int j = 0; j < 4; ++j) {
    int i = base + j;
    if (i < NNODES) { row_ptr[i] = run; cursor[i] = run; run += v[j]; }
  }
}

__global__ __launch_bounds__(256) void k_scatter(
    const int* __restrict__ g_row, const int* __restrict__ g_col,
    const float* __restrict__ g_val, int* __restrict__ cursor,
    int* __restrict__ col_s, float* __restrict__ val_s) {
  int e = blockIdx.x * 256 + threadIdx.x;
  if (e < NEDGES) {
    int r = g_row[e];
    int p = atomicAdd(&cursor[r], 1);
    col_s[p] = g_col[e];
    val_s[p] = g_val[e];
  }
}

// ---------------------------------------------------------------------------
// SpMM v3: wave per row, 8 edges/iter (2 per lane), branchless 16B gathers.
// lane: eg = lane>>4 (edge subgroup 0-3), fg = (lane&15)*8 (feature octet).
// Invalid edges clamp to row 0 with weight 0 so loads always issue.
// Butterfly (16,32) sums edge subgroups; lanes 0-15 store.
// ---------------------------------------------------------------------------
template<bool WRITE_BF>
__global__ __launch_bounds__(256) void k_spmm(
    const int* __restrict__ row_ptr, const int* __restrict__ col_s,
    const float* __restrict__ val_s, const bf16* __restrict__ X,
    float* __restrict__ Y, bf16* __restrict__ Yb)
{
  int w = (int)((blockIdx.x * 256u + threadIdx.x) >> 6);
  if (w >= NNODES) return;
  const int lane = threadIdx.x & 63;
  const int eg = lane >> 4;
  const int fg = (lane & 15) * 8;
  const int s = row_ptr[w], e = row_ptr[w + 1];

  float acc[8] = {0.f, 0.f, 0.f, 0.f, 0.f, 0.f, 0.f, 0.f};
  for (int i = s; i < e; i += 8) {
    int i0 = i + eg, i1 = i + 4 + eg;
    int   c0 = 0,  c1 = 0;
    float v0 = 0.f, v1 = 0.f;
    if (i0 < e) { c0 = col_s[i0]; v0 = val_s[i0]; }
    if (i1 < e) { c1 = col_s[i1]; v1 = val_s[i1]; }
    short8v x0 = *(const short8v*)&X[(size_t)c0 * 128 + fg];
    short8v x1 = *(const short8v*)&X[(size_t)c1 * 128 + fg];
    #pragma unroll
    for (int j = 0; j < 8; ++j)
      acc[j] += v0 * b2f_(x0[j]) + v1 * b2f_(x1[j]);
  }
  #pragma unroll
  for (int j = 0; j < 8; ++j) {
    acc[j] += __shfl_xor(acc[j], 16, 64);
    acc[j] += __shfl_xor(acc[j], 32, 64);
  }
  if (lane < 16) {
    float4 o0 = make_float4(acc[0], acc[1], acc[2], acc[3]);
    float4 o1 = make_float4(acc[4], acc[5], acc[6], acc[7]);
    *(float4*)&Y[(size_t)w * 128 + fg]     = o0;
    *(float4*)&Y[(size_t)w * 128 + fg + 4] = o1;
    if (WRITE_BF) {
      short8v ob;
      #pragma unroll
      for (int j = 0; j < 8; ++j) {
        __hip_bfloat16 h = __float2bfloat16(acc[j]);
        ob[j] = *(short*)&h;
      }
      *(short8v*)&Yb[(size_t)w * 128 + fg] = ob;
    }
  }
}

// ---------------------------------------------------------------------------
// Gather v2: 2 output rows per wave, float4 (16B) per lane, fused l2norm.
// ---------------------------------------------------------------------------
__global__ __launch_bounds__(256) void k_gather(
    const float* __restrict__ s1, const float* __restrict__ s2,
    const int* __restrict__ i0, const int* __restrict__ i1,
    const int* __restrict__ i2, const int* __restrict__ i3,
    float* __restrict__ out)
{
  long wid = ((long)blockIdx.x * 256 + threadIdx.x) >> 6;   // 0..399999
  int lane = threadIdx.x & 63;
  long gw = wid * 2 + (lane >> 5);                          // 0..799999
  int fl = (lane & 31) * 4;
  int o   = (int)(gw / 200000);
  int rem = (int)(gw % 200000);
  int l = rem / 100000;
  int i = rem % 100000;
  const int* idx = (o == 0) ? i0 : (o == 1) ? i1 : (o == 2) ? i2 : i3;
  int node = idx[i];
  const float* src = (l == 0) ? s1 : s2;
  float4 v = *(const float4*)&src[(size_t)node * 128 + fl];
  float ss = v.x * v.x + v.y * v.y + v.z * v.z + v.w * v.w;
  #pragma unroll
  for (int off = 1; off < 32; off <<= 1) ss += __shfl_xor(ss, off, 64);
  float inv = 1.0f / fmaxf(sqrtf(ss), 1e-12f);
  float4 ov = make_float4(v.x * inv, v.y * inv, v.z * inv, v.w * inv);
  *(float4*)&out[gw * 128 + fl] = ov;
}

__global__ void k_loss_final(const float* __restrict__ loss_acc, float* __restrict__ out) {
  if (threadIdx.x == 0)
    out[102400000] = loss_acc[0] * (1.0f / 50000000.0f);
}

// ---------------------------------------------------------------------------
extern "C" void kernel_launch(void* const* d_in, const int* in_sizes, int n_in,
                              void* d_out, int out_size, void* d_ws, size_t ws_size,
                              hipStream_t stream)
{
  const float* emb_attr = (const float*)d_in[0];
  const float* emb_node = (const float*)d_in[1];
  const float* W0 = (const float*)d_in[2];
  const float* b0 = (const float*)d_in[3];
  const float* W1 = (const float*)d_in[4];
  const float* b1 = (const float*)d_in[5];
  const float* H  = (const float*)d_in[6];
  const float* g_val = (const float*)d_in[7];
  const int* g_row = (const int*)d_in[8];
  const int* g_col = (const int*)d_in[9];
  const int* pos_src = (const int*)d_in[10];
  const int* pos_dst = (const int*)d_in[11];
  const int* neg_src = (const int*)d_in[12];
  const int* neg_dst = (const int*)d_in[13];
  float* out = (float*)d_out;

  const size_t NF = 12800000;
  const int NB = (NNODES + 1023) / 1024;               // 98 scan blocks

  char* base = (char*)d_out;
  bf16*  embn_bf = (bf16*)base;                        // 25.6 MB
  bf16*  Hacc_bf = embn_bf + NF;                       // 25.6 MB
  bf16*  y_bf    = Hacc_bf + NF;                       // 25.6 MB
  bf16*  s1_bf   = y_bf + NF;                          // 25.6 MB
  bf16*  W0t_bf  = s1_bf + NF;                         // 64 KB
  bf16*  W1t_bf  = W0t_bf + 32768;                     // 32 KB
  bf16*  attr_bf = W1t_bf + 16384;                     // 125 KB
  int*   row_ptr  = (int*)(attr_bf + 64000);
  int*   deg      = row_ptr + 100004;
  int*   cursor   = deg + 100000;
  int*   hrow_ptr = cursor + 100000;
  int*   hcnt     = hrow_ptr + 100004;
  int*   hcursor  = hcnt + 100000;
  int*   bsum     = hcursor + 100000;                  // 128
  int*   boff     = bsum + 128;                        // 128
  int*   col_s    = boff + 128;                        // 3.2M
  int*   hattr    = col_s + 3200000;                   // 1M
  int*   hnode    = hattr + HCAP;                      // 1M
  float* val_s    = (float*)(hnode + HCAP);            // 3.2M

  float* s1 = (float*)d_ws;                            // 51.2 MB
  float* s2 = s1 + NF;                                 // 51.2 MB
  float* loss_acc = s2 + NF;

  hipMemsetAsync(loss_acc, 0, 16, stream);
  hipMemsetAsync(deg, 0, NNODES * sizeof(int), stream);
  hipMemsetAsync(hcnt, 0, NNODES * sizeof(int), stream);

  // --- bf16 conversions ---
  k_cvt_bf<<<12500, 256, 0, stream>>>(emb_node, embn_bf, (int)NF);
  k_cvt_small<<<442, 256, 0, stream>>>(W0, W1, emb_attr, W0t_bf, W1t_bf, attr_bf);

  // --- sparse H extraction ---
  dim3 hgrid(NB, NATTRI);
  k_hnz_count<<<hgrid, 256, 0, stream>>>(H, hcnt);
  k_scan_p1<<<NB, 256, 0, stream>>>(hcnt, bsum);
  k_scan_p2<<<1, 128, 0, stream>>>(bsum, boff, hrow_ptr, NB);
  k_scan_p3<<<NB, 256, 0, stream>>>(hcnt, boff, hrow_ptr, hcursor);
  k_hnz_place<<<hgrid, 256, 0, stream>>>(H, hcursor, hattr, hnode);
  k_hacc_sparse<<<NNODES / 4, 256, 0, stream>>>(hrow_ptr, hattr, emb_attr, Hacc_bf);

  // --- loss: MFMA base + flat sparse correction ---
  dim3 lgrid((NNODES + 127) / 128, 4);
  k_loss_mfma<<<lgrid, 256, 0, stream>>>(embn_bf, attr_bf, loss_acc);
  k_loss_corr_flat<<<4096, 256, 0, stream>>>(hnode, hattr, hrow_ptr, emb_attr, emb_node, loss_acc);

  // --- edge CSR ---
  k_hist<<<(NEDGES + 255) / 256, 256, 0, stream>>>(g_row, deg);
  k_scan_p1<<<NB, 256, 0, stream>>>(deg, bsum);
  k_scan_p2<<<1, 128, 0, stream>>>(bsum, boff, row_ptr, NB);
  k_scan_p3<<<NB, 256, 0, stream>>>(deg, boff, row_ptr, cursor);
  k_scatter<<<(NEDGES + 255) / 256, 256, 0, stream>>>(g_row, g_col, g_val, cursor, col_s, val_s);

  // --- GNN layers ---
  const int ggrid = (NNODES + 127) / 128;   // 782
  k_gemm_mfma<256><<<ggrid, 256, 0, stream>>>(embn_bf, Hacc_bf, W0t_bf, b0, y_bf);
  k_spmm<true><<<(NNODES * 64) / 256, 256, 0, stream>>>(row_ptr, col_s, val_s, y_bf, s1, s1_bf);
  k_gemm_mfma<128><<<ggrid, 256, 0, stream>>>(s1_bf, (const bf16*)nullptr, W1t_bf, b1, y_bf);
  k_spmm<false><<<(NNODES * 64) / 256, 256, 0, stream>>>(row_ptr, col_s, val_s, y_bf, s2, (bf16*)nullptr);

  // --- outputs ---
  k_gather<<<100000, 256, 0, stream>>>(s1, s2, pos_src, pos_dst, neg_src, neg_dst, out);
  k_loss_final<<<1, 64, 0, stream>>>(loss_acc, out);
}